// Round 1
// baseline (16749.889 us; speedup 1.0000x reference)
//
#include <hip/hip_runtime.h>
#include <hip/hip_bf16.h>

#define NEG_SLOPE 0.01f
#define TILE_R 64
#define KC 32

__device__ __forceinline__ float lrelu(float x) { return x > 0.f ? x : NEG_SLOPE * x; }

__global__ void rmap_kernel(const int* __restrict__ batch, const int* __restrict__ root_idx,
                            int* __restrict__ rmap, int N) {
    for (int i = blockIdx.x * blockDim.x + threadIdx.x; i < N; i += gridDim.x * blockDim.x)
        rmap[i] = root_idx[batch[i]];
}

// h[i][c] = bias[c] for all i
__global__ void init_bias_kernel(float* __restrict__ h, const float* __restrict__ b, int N) {
    float4* h4 = (float4*)h;
    const float4* b4 = (const float4*)b;
    long long total = (long long)N * 32;
    for (long long i = blockIdx.x * (long long)blockDim.x + threadIdx.x; i < total;
         i += (long long)gridDim.x * blockDim.x)
        h4[i] = b4[i & 31];
}

// h[dst[e]] += vals[e] * xw[src[e]]  (edge-parallel, f32 atomics)
__global__ void scatter_kernel(const float* __restrict__ xw, const int* __restrict__ src,
                               const int* __restrict__ dst, const float* __restrict__ vals,
                               float* __restrict__ h, int E) {
    long long total = (long long)E * 32;  // (edge, 4-col group)
    for (long long idx = blockIdx.x * (long long)blockDim.x + threadIdx.x; idx < total;
         idx += (long long)gridDim.x * blockDim.x) {
        int e  = (int)(idx >> 5);
        int c4 = (int)(idx & 31);
        int s = src[e], d = dst[e];
        float v = vals[e];
        float4 x = *(const float4*)(xw + (size_t)s * 128 + c4 * 4);
        float* hp = h + (size_t)d * 128 + c4 * 4;
        atomicAdd(hp + 0, v * x.x);
        atomicAdd(hp + 1, v * x.y);
        atomicAdd(hp + 2, v * x.z);
        atomicAdd(hp + 3, v * x.w);
    }
}

// out[N,128] = act( concat(actA(A[N,128]), actB(B2[rmap][N,128])) @ W[K,128] (+ bias) )
template <int K, bool LRA, bool LRB, bool LROUT, bool HASB>
__global__ __launch_bounds__(256) void gemm_kernel(const float* __restrict__ A,
                                                   const float* __restrict__ B2,
                                                   const int* __restrict__ rmap,
                                                   const float* __restrict__ W,
                                                   const float* __restrict__ bias,
                                                   float* __restrict__ out, int N) {
    __shared__ float xs[KC][TILE_R];   // transposed x chunk: xs[kk][row]
    __shared__ float wsh[KC][128];     // W chunk
    const int tid = threadIdx.x;
    const int tc = tid & 15;           // 16 col-groups of 8
    const int tr = tid >> 4;           // 16 row-groups of 4
    const int row0 = blockIdx.x * TILE_R;

    float acc[4][8];
#pragma unroll
    for (int i = 0; i < 4; ++i)
#pragma unroll
        for (int j = 0; j < 8; ++j) acc[i][j] = 0.f;

    // x staging mapping: 4 threads per row, 8 floats each
    const int lrow = tid >> 2;
    const int part = tid & 3;
    const int grow = row0 + lrow;
    const int gr = grow < N ? grow : N - 1;

#pragma unroll
    for (int kc = 0; kc < K / KC; ++kc) {
        // ---- stage W chunk: KC x 128 = 4096 floats, 16/thread ----
        {
            const float* Wsrc = W + (size_t)kc * KC * 128;
            float* wdst = &wsh[0][0];
#pragma unroll
            for (int i = 0; i < 4; ++i) {
                int off = tid * 4 + i * 1024;
                *(float4*)(wdst + off) = *(const float4*)(Wsrc + off);
            }
        }
        // ---- stage x chunk (transposed) ----
        {
            float tmp[8];
            if (kc * KC < 128) {  // first 128 cols come from A
                const int kbase = kc * KC + part * 8;
                const float* sp = A + (size_t)gr * 128 + kbase;
                float4 v0 = *(const float4*)sp;
                float4 v1 = *(const float4*)(sp + 4);
                tmp[0] = v0.x; tmp[1] = v0.y; tmp[2] = v0.z; tmp[3] = v0.w;
                tmp[4] = v1.x; tmp[5] = v1.y; tmp[6] = v1.z; tmp[7] = v1.w;
                if (LRA) {
#pragma unroll
                    for (int j = 0; j < 8; ++j) tmp[j] = lrelu(tmp[j]);
                }
            } else {              // cols 128..255 come from gathered B2 rows
                const int kbase = kc * KC + part * 8 - 128;
                const int rr = rmap[gr];
                const float* sp = B2 + (size_t)rr * 128 + kbase;
                float4 v0 = *(const float4*)sp;
                float4 v1 = *(const float4*)(sp + 4);
                tmp[0] = v0.x; tmp[1] = v0.y; tmp[2] = v0.z; tmp[3] = v0.w;
                tmp[4] = v1.x; tmp[5] = v1.y; tmp[6] = v1.z; tmp[7] = v1.w;
                if (LRB) {
#pragma unroll
                    for (int j = 0; j < 8; ++j) tmp[j] = lrelu(tmp[j]);
                }
            }
#pragma unroll
            for (int j = 0; j < 8; ++j) xs[part * 8 + j][lrow] = tmp[j];
        }
        __syncthreads();
        // ---- compute ----
#pragma unroll
        for (int kk = 0; kk < KC; ++kk) {
            float a[4];
#pragma unroll
            for (int i = 0; i < 4; ++i) a[i] = xs[kk][tr * 4 + i];
            float4 w0 = *(float4*)&wsh[kk][tc * 8];
            float4 w1 = *(float4*)&wsh[kk][tc * 8 + 4];
            float wv[8] = {w0.x, w0.y, w0.z, w0.w, w1.x, w1.y, w1.z, w1.w};
#pragma unroll
            for (int i = 0; i < 4; ++i)
#pragma unroll
                for (int j = 0; j < 8; ++j) acc[i][j] = fmaf(a[i], wv[j], acc[i][j]);
        }
        __syncthreads();
    }

    // ---- epilogue ----
#pragma unroll
    for (int i = 0; i < 4; ++i) {
        int grr = row0 + tr * 4 + i;
        if (grr < N) {
            float o[8];
#pragma unroll
            for (int j = 0; j < 8; ++j) {
                float v = acc[i][j];
                if (HASB) v += bias[tc * 8 + j];
                if (LROUT) v = lrelu(v);
                o[j] = v;
            }
            float4* op = (float4*)(out + (size_t)grr * 128 + tc * 8);
            op[0] = make_float4(o[0], o[1], o[2], o[3]);
            op[1] = make_float4(o[4], o[5], o[6], o[7]);
        }
    }
}

extern "C" void kernel_launch(void* const* d_in, const int* in_sizes, int n_in,
                              void* d_out, int out_size, void* d_ws, size_t ws_size,
                              hipStream_t stream) {
    const float* features = (const float*)d_in[0];
    const float* values   = (const float*)d_in[1];
    const float* W1 = (const float*)d_in[2];
    const float* b1 = (const float*)d_in[3];
    const float* W2 = (const float*)d_in[4];
    const float* b2 = (const float*)d_in[5];
    const float* Wl = (const float*)d_in[6];
    const float* bl = (const float*)d_in[7];
    const int* adjs     = (const int*)d_in[8];
    const int* root_idx = (const int*)d_in[9];
    const int* batch    = (const int*)d_in[12];
    float* out = (float*)d_out;

    const int N = in_sizes[0] / 128;
    const int E = in_sizes[1];
    const int* src = adjs;
    const int* dst = adjs + E;

    const size_t nf = (size_t)N * 128;
    float* bufA = (float*)d_ws;      // xw1 / xw2
    float* h1   = bufA + nf;         // conv1 output (pre-activation + b1)
    float* h2   = h1 + nf;           // conv2 output (pre-lrelu, + b2)
    int*  rmap  = (int*)(h2 + nf);   // node -> root-node index

    const int gblocks = (N + TILE_R - 1) / TILE_R;

    rmap_kernel<<<256, 256, 0, stream>>>(batch, root_idx, rmap, N);

    // xw1 = features @ W1
    gemm_kernel<128, false, false, false, false>
        <<<gblocks, 256, 0, stream>>>(features, nullptr, nullptr, W1, nullptr, bufA, N);

    // h1 = b1 + scatter(values * xw1[src] -> dst)
    init_bias_kernel<<<2048, 256, 0, stream>>>(h1, b1, N);
    scatter_kernel<<<4096, 256, 0, stream>>>(bufA, src, dst, values, h1, E);

    // xw2 = concat(lrelu(h1), lrelu(features[root])) @ W2
    gemm_kernel<256, true, true, false, false>
        <<<gblocks, 256, 0, stream>>>(h1, features, rmap, W2, nullptr, bufA, N);

    // h2raw = b2 + scatter(values * xw2[src] -> dst)
    init_bias_kernel<<<2048, 256, 0, stream>>>(h2, b2, N);
    scatter_kernel<<<4096, 256, 0, stream>>>(bufA, src, dst, values, h2, E);

    // out = lrelu( concat(lrelu(h2raw), h1[root]) @ Wl + bl )
    gemm_kernel<256, true, false, true, true>
        <<<gblocks, 256, 0, stream>>>(h2, h1, rmap, Wl, bl, out, N);
}

// Round 2
// 2947.579 us; speedup vs baseline: 5.6826x; 5.6826x over previous
//
#include <hip/hip_runtime.h>
#include <hip/hip_bf16.h>

#define NEG_SLOPE 0.01f
#define TILE_R 64
#define KC 32

__device__ __forceinline__ float lrelu(float x) { return x > 0.f ? x : NEG_SLOPE * x; }

__global__ void rmap_kernel(const int* __restrict__ batch, const int* __restrict__ root_idx,
                            int* __restrict__ rmap, int N) {
    for (int i = blockIdx.x * blockDim.x + threadIdx.x; i < N; i += gridDim.x * blockDim.x)
        rmap[i] = root_idx[batch[i]];
}

// h[i][c] = bias[c] for all i
__global__ void init_bias_kernel(float* __restrict__ h, const float* __restrict__ b, int N) {
    float4* h4 = (float4*)h;
    const float4* b4 = (const float4*)b;
    long long total = (long long)N * 32;
    for (long long i = blockIdx.x * (long long)blockDim.x + threadIdx.x; i < total;
         i += (long long)gridDim.x * blockDim.x)
        h4[i] = b4[i & 31];
}

// h[dst[e]] += vals[e] * xw[src[e]]  (edge-parallel, f32 atomics)
__global__ void scatter_kernel(const float* __restrict__ xw, const int* __restrict__ src,
                               const int* __restrict__ dst, const float* __restrict__ vals,
                               float* __restrict__ h, int E) {
    long long total = (long long)E * 32;  // (edge, 4-col group)
    for (long long idx = blockIdx.x * (long long)blockDim.x + threadIdx.x; idx < total;
         idx += (long long)gridDim.x * blockDim.x) {
        int e  = (int)(idx >> 5);
        int c4 = (int)(idx & 31);
        int s = src[e], d = dst[e];
        float v = vals[e];
        float4 x = *(const float4*)(xw + (size_t)s * 128 + c4 * 4);
        float* hp = h + (size_t)d * 128 + c4 * 4;
        atomicAdd(hp + 0, v * x.x);
        atomicAdd(hp + 1, v * x.y);
        atomicAdd(hp + 2, v * x.z);
        atomicAdd(hp + 3, v * x.w);
    }
}

// out[N,128] = act( concat(actA(A[N,128]), actB(B2[rmap][N,128])) @ W[K,128] (+ bias) )
template <int K, bool LRA, bool LRB, bool LROUT, bool HASB>
__global__ __launch_bounds__(256) void gemm_kernel(const float* __restrict__ A,
                                                   const float* __restrict__ B2,
                                                   const int* __restrict__ rmap,
                                                   const float* __restrict__ W,
                                                   const float* __restrict__ bias,
                                                   float* __restrict__ out, int N) {
    __shared__ float xs[KC][TILE_R + 1];  // transposed x chunk, padded stride 65
    __shared__ float wsh[KC][128];        // W chunk
    const int tid = threadIdx.x;
    const int tc = tid & 15;           // 16 col-groups of 8
    const int tr = tid >> 4;           // 16 row-groups of 4
    const int row0 = blockIdx.x * TILE_R;

    float acc[4][8];
#pragma unroll
    for (int i = 0; i < 4; ++i)
#pragma unroll
        for (int j = 0; j < 8; ++j) acc[i][j] = 0.f;

    // x staging mapping: 4 threads per row, 8 floats each
    const int lrow = tid >> 2;
    const int part = tid & 3;
    const int grow = row0 + lrow;
    const int gr = grow < N ? grow : N - 1;

#pragma unroll 1   // DO NOT unroll: full unroll spilled 10 GB of scratch (round 1)
    for (int kc = 0; kc < K / KC; ++kc) {
        // ---- stage W chunk: KC x 128 = 4096 floats, 16/thread ----
        {
            const float* Wsrc = W + (size_t)kc * KC * 128;
            float* wdst = &wsh[0][0];
#pragma unroll
            for (int i = 0; i < 4; ++i) {
                int off = tid * 4 + i * 1024;
                *(float4*)(wdst + off) = *(const float4*)(Wsrc + off);
            }
        }
        // ---- stage x chunk (transposed) ----
        {
            float tmp[8];
            if (kc * KC < 128) {  // first 128 cols come from A
                const int kbase = kc * KC + part * 8;
                const float* sp = A + (size_t)gr * 128 + kbase;
                float4 v0 = *(const float4*)sp;
                float4 v1 = *(const float4*)(sp + 4);
                tmp[0] = v0.x; tmp[1] = v0.y; tmp[2] = v0.z; tmp[3] = v0.w;
                tmp[4] = v1.x; tmp[5] = v1.y; tmp[6] = v1.z; tmp[7] = v1.w;
                if (LRA) {
#pragma unroll
                    for (int j = 0; j < 8; ++j) tmp[j] = lrelu(tmp[j]);
                }
            } else {              // cols 128..255 come from gathered B2 rows
                const int kbase = kc * KC + part * 8 - 128;
                const int rr = rmap[gr];
                const float* sp = B2 + (size_t)rr * 128 + kbase;
                float4 v0 = *(const float4*)sp;
                float4 v1 = *(const float4*)(sp + 4);
                tmp[0] = v0.x; tmp[1] = v0.y; tmp[2] = v0.z; tmp[3] = v0.w;
                tmp[4] = v1.x; tmp[5] = v1.y; tmp[6] = v1.z; tmp[7] = v1.w;
                if (LRB) {
#pragma unroll
                    for (int j = 0; j < 8; ++j) tmp[j] = lrelu(tmp[j]);
                }
            }
#pragma unroll
            for (int j = 0; j < 8; ++j) xs[part * 8 + j][lrow] = tmp[j];
        }
        __syncthreads();
        // ---- compute ----
#pragma unroll
        for (int kk = 0; kk < KC; ++kk) {
            float a[4];
#pragma unroll
            for (int i = 0; i < 4; ++i) a[i] = xs[kk][tr * 4 + i];
            float4 w0 = *(float4*)&wsh[kk][tc * 8];
            float4 w1 = *(float4*)&wsh[kk][tc * 8 + 4];
            float wv[8] = {w0.x, w0.y, w0.z, w0.w, w1.x, w1.y, w1.z, w1.w};
#pragma unroll
            for (int i = 0; i < 4; ++i)
#pragma unroll
                for (int j = 0; j < 8; ++j) acc[i][j] = fmaf(a[i], wv[j], acc[i][j]);
        }
        __syncthreads();
    }

    // ---- epilogue ----
#pragma unroll
    for (int i = 0; i < 4; ++i) {
        int grr = row0 + tr * 4 + i;
        if (grr < N) {
            float o[8];
#pragma unroll
            for (int j = 0; j < 8; ++j) {
                float v = acc[i][j];
                if (HASB) v += bias[tc * 8 + j];
                if (LROUT) v = lrelu(v);
                o[j] = v;
            }
            float4* op = (float4*)(out + (size_t)grr * 128 + tc * 8);
            op[0] = make_float4(o[0], o[1], o[2], o[3]);
            op[1] = make_float4(o[4], o[5], o[6], o[7]);
        }
    }
}

extern "C" void kernel_launch(void* const* d_in, const int* in_sizes, int n_in,
                              void* d_out, int out_size, void* d_ws, size_t ws_size,
                              hipStream_t stream) {
    const float* features = (const float*)d_in[0];
    const float* values   = (const float*)d_in[1];
    const float* W1 = (const float*)d_in[2];
    const float* b1 = (const float*)d_in[3];
    const float* W2 = (const float*)d_in[4];
    const float* b2 = (const float*)d_in[5];
    const float* Wl = (const float*)d_in[6];
    const float* bl = (const float*)d_in[7];
    const int* adjs     = (const int*)d_in[8];
    const int* root_idx = (const int*)d_in[9];
    const int* batch    = (const int*)d_in[12];
    float* out = (float*)d_out;

    const int N = in_sizes[0] / 128;
    const int E = in_sizes[1];
    const int* src = adjs;
    const int* dst = adjs + E;

    const size_t nf = (size_t)N * 128;
    float* bufA = (float*)d_ws;      // xw1 / xw2
    float* h1   = bufA + nf;         // conv1 output (pre-activation + b1)
    float* h2   = h1 + nf;           // conv2 output (pre-lrelu, + b2)
    int*  rmap  = (int*)(h2 + nf);   // node -> root-node index

    const int gblocks = (N + TILE_R - 1) / TILE_R;

    rmap_kernel<<<256, 256, 0, stream>>>(batch, root_idx, rmap, N);

    // xw1 = features @ W1
    gemm_kernel<128, false, false, false, false>
        <<<gblocks, 256, 0, stream>>>(features, nullptr, nullptr, W1, nullptr, bufA, N);

    // h1 = b1 + scatter(values * xw1[src] -> dst)
    init_bias_kernel<<<2048, 256, 0, stream>>>(h1, b1, N);
    scatter_kernel<<<4096, 256, 0, stream>>>(bufA, src, dst, values, h1, E);

    // xw2 = concat(lrelu(h1), lrelu(features[root])) @ W2
    gemm_kernel<256, true, true, false, false>
        <<<gblocks, 256, 0, stream>>>(h1, features, rmap, W2, nullptr, bufA, N);

    // h2raw = b2 + scatter(values * xw2[src] -> dst)
    init_bias_kernel<<<2048, 256, 0, stream>>>(h2, b2, N);
    scatter_kernel<<<4096, 256, 0, stream>>>(bufA, src, dst, values, h2, E);

    // out = lrelu( concat(lrelu(h2raw), h1[root]) @ Wl + bl )
    gemm_kernel<256, true, false, true, true>
        <<<gblocks, 256, 0, stream>>>(h2, h1, rmap, Wl, bl, out, N);
}

// Round 3
// 474.650 us; speedup vs baseline: 35.2890x; 6.2100x over previous
//
#include <hip/hip_runtime.h>
#include <hip/hip_bf16.h>

#define NEG_SLOPE 0.01f
#define TILE_R 64
#define KC 32
#define SCAN_CHUNK 1024

__device__ __forceinline__ float lrelu(float x) { return x > 0.f ? x : NEG_SLOPE * x; }

__global__ void rmap_kernel(const int* __restrict__ batch, const int* __restrict__ root_idx,
                            int* __restrict__ rmap, int N) {
    for (int i = blockIdx.x * blockDim.x + threadIdx.x; i < N; i += gridDim.x * blockDim.x)
        rmap[i] = root_idx[batch[i]];
}

__global__ void zero_kernel(int* __restrict__ p, int n) {
    for (int i = blockIdx.x * blockDim.x + threadIdx.x; i < n; i += gridDim.x * blockDim.x)
        p[i] = 0;
}

// deg[dst[e]]++
__global__ void count_kernel(const int* __restrict__ dst, int* __restrict__ deg, int E) {
    for (int e = blockIdx.x * blockDim.x + threadIdx.x; e < E; e += gridDim.x * blockDim.x)
        atomicAdd(&deg[dst[e]], 1);
}

// per-chunk exclusive scan of deg -> rowstart (partial), chunksum[b] = chunk total
__global__ __launch_bounds__(256) void scan1_kernel(const int* __restrict__ deg,
                                                    int* __restrict__ rowstart,
                                                    int* __restrict__ chunksum, int N) {
    __shared__ int ts[256];
    const int b = blockIdx.x, t = threadIdx.x;
    const int base = b * SCAN_CHUNK + t * 4;
    int v[4], s = 0;
#pragma unroll
    for (int j = 0; j < 4; ++j) {
        v[j] = (base + j < N) ? deg[base + j] : 0;
        s += v[j];
    }
    ts[t] = s;
    __syncthreads();
    for (int off = 1; off < 256; off <<= 1) {
        int x = (t >= off) ? ts[t - off] : 0;
        __syncthreads();
        ts[t] += x;
        __syncthreads();
    }
    int run = ts[t] - s;  // exclusive prefix of this thread's 4-group
#pragma unroll
    for (int j = 0; j < 4; ++j) {
        if (base + j < N) rowstart[base + j] = run;
        run += v[j];
    }
    if (t == 255) chunksum[b] = ts[255];
}

// serial scan of chunk sums (nchunks ~ 49); also rowstart[N] = E
__global__ void scan2_kernel(const int* __restrict__ chunksum, int* __restrict__ chunkoff,
                             int nchunks, int* __restrict__ rowstart, int N, int E) {
    if (blockIdx.x == 0 && threadIdx.x == 0) {
        int acc = 0;
        for (int i = 0; i < nchunks; ++i) { chunkoff[i] = acc; acc += chunksum[i]; }
        rowstart[N] = E;
    }
}

// rowstart[i] += chunkoff[i/CHUNK]; cursor[i] = rowstart[i]
__global__ void scan3_kernel(int* __restrict__ rowstart, const int* __restrict__ chunkoff,
                             int* __restrict__ cursor, int N) {
    for (int i = blockIdx.x * blockDim.x + threadIdx.x; i < N; i += gridDim.x * blockDim.x) {
        int v = rowstart[i] + chunkoff[i / SCAN_CHUNK];
        rowstart[i] = v;
        cursor[i] = v;
    }
}

// counting-sort edges by dst: esrc/eval permuted into CSR buckets
__global__ void fill_kernel(const int* __restrict__ src, const int* __restrict__ dst,
                            const float* __restrict__ vals, int* __restrict__ cursor,
                            int* __restrict__ esrc, float* __restrict__ eval, int E) {
    for (int e = blockIdx.x * blockDim.x + threadIdx.x; e < E; e += gridDim.x * blockDim.x) {
        int d = dst[e];
        int pos = atomicAdd(&cursor[d], 1);
        esrc[pos] = src[e];
        eval[pos] = vals[e];
    }
}

// h[i] = bias + sum_{e in CSR[i]} eval[e] * xw[esrc[e]]   (one wave per node)
__global__ __launch_bounds__(256) void gather_kernel(const float* __restrict__ xw,
                                                     const int* __restrict__ rowstart,
                                                     const int* __restrict__ esrc,
                                                     const float* __restrict__ eval,
                                                     const float* __restrict__ bias,
                                                     float* __restrict__ h, int N) {
    const int node = blockIdx.x * 4 + (threadIdx.x >> 6);
    const int lane = threadIdx.x & 63;
    if (node >= N) return;
    const int s0 = rowstart[node], s1 = rowstart[node + 1];
    float2 acc = *(const float2*)(bias + lane * 2);
    int e = s0;
    for (; e + 2 <= s1; e += 2) {
        int sa = esrc[e], sb = esrc[e + 1];
        float va = eval[e], vb = eval[e + 1];
        float2 xa = *(const float2*)(xw + (size_t)sa * 128 + lane * 2);
        float2 xb = *(const float2*)(xw + (size_t)sb * 128 + lane * 2);
        acc.x = fmaf(va, xa.x, acc.x);
        acc.y = fmaf(va, xa.y, acc.y);
        acc.x = fmaf(vb, xb.x, acc.x);
        acc.y = fmaf(vb, xb.y, acc.y);
    }
    if (e < s1) {
        int sa = esrc[e];
        float va = eval[e];
        float2 xa = *(const float2*)(xw + (size_t)sa * 128 + lane * 2);
        acc.x = fmaf(va, xa.x, acc.x);
        acc.y = fmaf(va, xa.y, acc.y);
    }
    *(float2*)(h + (size_t)node * 128 + lane * 2) = acc;
}

// out[N,128] = act( concat(actA(A[N,128]), actB(B2[rmap][N,128])) @ W[K,128] (+ bias) )
template <int K, bool LRA, bool LRB, bool LROUT, bool HASB>
__global__ __launch_bounds__(256) void gemm_kernel(const float* __restrict__ A,
                                                   const float* __restrict__ B2,
                                                   const int* __restrict__ rmap,
                                                   const float* __restrict__ W,
                                                   const float* __restrict__ bias,
                                                   float* __restrict__ out, int N) {
    __shared__ float xs[KC][TILE_R + 1];  // transposed x chunk, padded stride 65
    __shared__ float wsh[KC][128];        // W chunk
    const int tid = threadIdx.x;
    const int tc = tid & 15;           // 16 col-groups of 8
    const int tr = tid >> 4;           // 16 row-groups of 4
    const int row0 = blockIdx.x * TILE_R;

    float acc[4][8];
#pragma unroll
    for (int i = 0; i < 4; ++i)
#pragma unroll
        for (int j = 0; j < 8; ++j) acc[i][j] = 0.f;

    // x staging mapping: 4 threads per row, 8 floats each
    const int lrow = tid >> 2;
    const int part = tid & 3;
    const int grow = row0 + lrow;
    const int gr = grow < N ? grow : N - 1;

#pragma unroll 1   // DO NOT unroll: full unroll spilled 10 GB of scratch (round 1)
    for (int kc = 0; kc < K / KC; ++kc) {
        // ---- stage W chunk: KC x 128 = 4096 floats, 16/thread ----
        {
            const float* Wsrc = W + (size_t)kc * KC * 128;
            float* wdst = &wsh[0][0];
#pragma unroll
            for (int i = 0; i < 4; ++i) {
                int off = tid * 4 + i * 1024;
                *(float4*)(wdst + off) = *(const float4*)(Wsrc + off);
            }
        }
        // ---- stage x chunk (transposed) ----
        {
            float tmp[8];
            if (kc * KC < 128) {  // first 128 cols come from A
                const int kbase = kc * KC + part * 8;
                const float* sp = A + (size_t)gr * 128 + kbase;
                float4 v0 = *(const float4*)sp;
                float4 v1 = *(const float4*)(sp + 4);
                tmp[0] = v0.x; tmp[1] = v0.y; tmp[2] = v0.z; tmp[3] = v0.w;
                tmp[4] = v1.x; tmp[5] = v1.y; tmp[6] = v1.z; tmp[7] = v1.w;
                if (LRA) {
#pragma unroll
                    for (int j = 0; j < 8; ++j) tmp[j] = lrelu(tmp[j]);
                }
            } else {              // cols 128..255 come from gathered B2 rows
                const int kbase = kc * KC + part * 8 - 128;
                const int rr = rmap[gr];
                const float* sp = B2 + (size_t)rr * 128 + kbase;
                float4 v0 = *(const float4*)sp;
                float4 v1 = *(const float4*)(sp + 4);
                tmp[0] = v0.x; tmp[1] = v0.y; tmp[2] = v0.z; tmp[3] = v0.w;
                tmp[4] = v1.x; tmp[5] = v1.y; tmp[6] = v1.z; tmp[7] = v1.w;
                if (LRB) {
#pragma unroll
                    for (int j = 0; j < 8; ++j) tmp[j] = lrelu(tmp[j]);
                }
            }
#pragma unroll
            for (int j = 0; j < 8; ++j) xs[part * 8 + j][lrow] = tmp[j];
        }
        __syncthreads();
        // ---- compute ----
#pragma unroll
        for (int kk = 0; kk < KC; ++kk) {
            float a[4];
#pragma unroll
            for (int i = 0; i < 4; ++i) a[i] = xs[kk][tr * 4 + i];
            float4 w0 = *(float4*)&wsh[kk][tc * 8];
            float4 w1 = *(float4*)&wsh[kk][tc * 8 + 4];
            float wv[8] = {w0.x, w0.y, w0.z, w0.w, w1.x, w1.y, w1.z, w1.w};
#pragma unroll
            for (int i = 0; i < 4; ++i)
#pragma unroll
                for (int j = 0; j < 8; ++j) acc[i][j] = fmaf(a[i], wv[j], acc[i][j]);
        }
        __syncthreads();
    }

    // ---- epilogue ----
#pragma unroll
    for (int i = 0; i < 4; ++i) {
        int grr = row0 + tr * 4 + i;
        if (grr < N) {
            float o[8];
#pragma unroll
            for (int j = 0; j < 8; ++j) {
                float v = acc[i][j];
                if (HASB) v += bias[tc * 8 + j];
                if (LROUT) v = lrelu(v);
                o[j] = v;
            }
            float4* op = (float4*)(out + (size_t)grr * 128 + tc * 8);
            op[0] = make_float4(o[0], o[1], o[2], o[3]);
            op[1] = make_float4(o[4], o[5], o[6], o[7]);
        }
    }
}

extern "C" void kernel_launch(void* const* d_in, const int* in_sizes, int n_in,
                              void* d_out, int out_size, void* d_ws, size_t ws_size,
                              hipStream_t stream) {
    const float* features = (const float*)d_in[0];
    const float* values   = (const float*)d_in[1];
    const float* W1 = (const float*)d_in[2];
    const float* b1 = (const float*)d_in[3];
    const float* W2 = (const float*)d_in[4];
    const float* b2 = (const float*)d_in[5];
    const float* Wl = (const float*)d_in[6];
    const float* bl = (const float*)d_in[7];
    const int* adjs     = (const int*)d_in[8];
    const int* root_idx = (const int*)d_in[9];
    const int* batch    = (const int*)d_in[12];
    float* out = (float*)d_out;

    const int N = in_sizes[0] / 128;
    const int E = in_sizes[1];
    const int* src = adjs;
    const int* dst = adjs + E;

    const size_t nf = (size_t)N * 128;
    float* bufA = (float*)d_ws;        // xw1 / xw2
    float* h1   = bufA + nf;           // conv1 output (+b1)
    float* h2   = h1 + nf;             // conv2 output (pre-lrelu, +b2)
    float* eval = h2 + nf;             // permuted edge weights [E]
    int*  esrc     = (int*)(eval + E); // permuted edge sources [E]
    int*  rmap     = esrc + E;         // node -> root-node index [N]
    int*  deg      = rmap + N;         // degree histogram [N]
    int*  rowstart = deg + N;          // CSR row offsets [N+1]
    int*  cursor   = rowstart + N + 1; // fill cursors [N]
    int*  chunksum = cursor + N;       // per-chunk sums [nchunks]
    int*  chunkoff = chunksum + 128;   // per-chunk offsets [nchunks]

    const int nchunks = (N + SCAN_CHUNK - 1) / SCAN_CHUNK;
    const int gblocks = (N + TILE_R - 1) / TILE_R;

    // ---- CSR build (once; shared by both convs) ----
    zero_kernel<<<64, 256, 0, stream>>>(deg, N);
    rmap_kernel<<<64, 256, 0, stream>>>(batch, root_idx, rmap, N);
    count_kernel<<<1024, 256, 0, stream>>>(dst, deg, E);
    scan1_kernel<<<nchunks, 256, 0, stream>>>(deg, rowstart, chunksum, N);
    scan2_kernel<<<1, 64, 0, stream>>>(chunksum, chunkoff, nchunks, rowstart, N, E);
    scan3_kernel<<<64, 256, 0, stream>>>(rowstart, chunkoff, cursor, N);
    fill_kernel<<<1024, 256, 0, stream>>>(src, dst, values, cursor, esrc, eval, E);

    // ---- conv1: xw1 = features @ W1 ; h1 = b1 + gather ----
    gemm_kernel<128, false, false, false, false>
        <<<gblocks, 256, 0, stream>>>(features, nullptr, nullptr, W1, nullptr, bufA, N);
    gather_kernel<<<(N + 3) / 4, 256, 0, stream>>>(bufA, rowstart, esrc, eval, b1, h1, N);

    // ---- conv2: xw2 = concat(lrelu(h1), lrelu(features[root])) @ W2 ; h2 = b2 + gather ----
    gemm_kernel<256, true, true, false, false>
        <<<gblocks, 256, 0, stream>>>(h1, features, rmap, W2, nullptr, bufA, N);
    gather_kernel<<<(N + 3) / 4, 256, 0, stream>>>(bufA, rowstart, esrc, eval, b2, h2, N);

    // ---- out = lrelu( concat(lrelu(h2), h1[root]) @ Wl + bl ) ----
    gemm_kernel<256, true, false, true, true>
        <<<gblocks, 256, 0, stream>>>(h2, h1, rmap, Wl, bl, out, N);
}

// Round 5
// 383.802 us; speedup vs baseline: 43.6420x; 1.2367x over previous
//
#include <hip/hip_runtime.h>
#include <hip/hip_bf16.h>

#define NEG_SLOPE 0.01f
#define SCAN_CHUNK 1024

typedef __attribute__((ext_vector_type(8))) short short8;
typedef __attribute__((ext_vector_type(4))) float f32x4;

__device__ __forceinline__ float lrelu(float x) { return x > 0.f ? x : NEG_SLOPE * x; }

// f32 -> bf16 bits, round-to-nearest-even
__device__ __forceinline__ short f2bf(float f) {
    unsigned u = __builtin_bit_cast(unsigned, f);
    u += 0x7fffu + ((u >> 16) & 1u);
    return (short)(u >> 16);
}

__global__ void rmap_kernel(const int* __restrict__ batch, const int* __restrict__ root_idx,
                            int* __restrict__ rmap, int N) {
    for (int i = blockIdx.x * blockDim.x + threadIdx.x; i < N; i += gridDim.x * blockDim.x)
        rmap[i] = root_idx[batch[i]];
}

__global__ void zero_kernel(int* __restrict__ p, int n) {
    for (int i = blockIdx.x * blockDim.x + threadIdx.x; i < n; i += gridDim.x * blockDim.x)
        p[i] = 0;
}

// transpose + convert: wt[c*K + k] = bf16(W[k*128 + c]);  W is [K][128]
__global__ void wxpose_kernel(const float* __restrict__ W, short* __restrict__ wt, int K) {
    int idx = blockIdx.x * blockDim.x + threadIdx.x;
    if (idx < K * 128) {
        int k = idx >> 7, c = idx & 127;
        wt[c * K + k] = f2bf(W[idx]);
    }
}

// deg[dst[e]]++
__global__ void count_kernel(const int* __restrict__ dst, int* __restrict__ deg, int E) {
    for (int e = blockIdx.x * blockDim.x + threadIdx.x; e < E; e += gridDim.x * blockDim.x)
        atomicAdd(&deg[dst[e]], 1);
}

__global__ __launch_bounds__(256) void scan1_kernel(const int* __restrict__ deg,
                                                    int* __restrict__ rowstart,
                                                    int* __restrict__ chunksum, int N) {
    __shared__ int ts[256];
    const int b = blockIdx.x, t = threadIdx.x;
    const int base = b * SCAN_CHUNK + t * 4;
    int v[4], s = 0;
#pragma unroll
    for (int j = 0; j < 4; ++j) {
        v[j] = (base + j < N) ? deg[base + j] : 0;
        s += v[j];
    }
    ts[t] = s;
    __syncthreads();
    for (int off = 1; off < 256; off <<= 1) {
        int x = (t >= off) ? ts[t - off] : 0;
        __syncthreads();
        ts[t] += x;
        __syncthreads();
    }
    int run = ts[t] - s;
#pragma unroll
    for (int j = 0; j < 4; ++j) {
        if (base + j < N) rowstart[base + j] = run;
        run += v[j];
    }
    if (t == 255) chunksum[b] = ts[255];
}

__global__ void scan2_kernel(const int* __restrict__ chunksum, int* __restrict__ chunkoff,
                             int nchunks, int* __restrict__ rowstart, int N, int E) {
    if (blockIdx.x == 0 && threadIdx.x == 0) {
        int acc = 0;
        for (int i = 0; i < nchunks; ++i) { chunkoff[i] = acc; acc += chunksum[i]; }
        rowstart[N] = E;
    }
}

__global__ void scan3_kernel(int* __restrict__ rowstart, const int* __restrict__ chunkoff,
                             int* __restrict__ cursor, int N) {
    for (int i = blockIdx.x * blockDim.x + threadIdx.x; i < N; i += gridDim.x * blockDim.x) {
        int v = rowstart[i] + chunkoff[i / SCAN_CHUNK];
        rowstart[i] = v;
        cursor[i] = v;
    }
}

__global__ void fill_kernel(const int* __restrict__ src, const int* __restrict__ dst,
                            const float* __restrict__ vals, int* __restrict__ cursor,
                            int* __restrict__ esrc, float* __restrict__ eval, int E) {
    for (int e = blockIdx.x * blockDim.x + threadIdx.x; e < E; e += gridDim.x * blockDim.x) {
        int d = dst[e];
        int pos = atomicAdd(&cursor[d], 1);
        esrc[pos] = src[e];
        eval[pos] = vals[e];
    }
}

// h[i] = bias + sum_{e in CSR[i]} eval[e] * xw[esrc[e]]   (one wave per node)
__global__ __launch_bounds__(256) void gather_kernel(const float* __restrict__ xw,
                                                     const int* __restrict__ rowstart,
                                                     const int* __restrict__ esrc,
                                                     const float* __restrict__ eval,
                                                     const float* __restrict__ bias,
                                                     float* __restrict__ h, int N) {
    const int node = blockIdx.x * 4 + (threadIdx.x >> 6);
    const int lane = threadIdx.x & 63;
    if (node >= N) return;
    const int s0 = rowstart[node], s1 = rowstart[node + 1];
    float2 acc = *(const float2*)(bias + lane * 2);
    int e = s0;
    for (; e + 2 <= s1; e += 2) {
        int sa = esrc[e], sb = esrc[e + 1];
        float va = eval[e], vb = eval[e + 1];
        float2 xa = *(const float2*)(xw + (size_t)sa * 128 + lane * 2);
        float2 xb = *(const float2*)(xw + (size_t)sb * 128 + lane * 2);
        acc.x = fmaf(va, xa.x, acc.x);
        acc.y = fmaf(va, xa.y, acc.y);
        acc.x = fmaf(vb, xb.x, acc.x);
        acc.y = fmaf(vb, xb.y, acc.y);
    }
    if (e < s1) {
        int sa = esrc[e];
        float va = eval[e];
        float2 xa = *(const float2*)(xw + (size_t)sa * 128 + lane * 2);
        acc.x = fmaf(va, xa.x, acc.x);
        acc.y = fmaf(va, xa.y, acc.y);
    }
    *(float2*)(h + (size_t)node * 128 + lane * 2) = acc;
}

// MFMA GEMM: out[N,128] = act( concat(actA(A), actB(B2[rmap])) @ W (+bias) )
// Wt is pre-transposed bf16: Wt[c*K + k]. Block: 64 rows, 4 waves, wave w -> rows w*16..+16.
template <int K, bool LRA, bool LRB, bool LROUT, bool HASB>
__global__ __launch_bounds__(256) void mgemm_kernel(const float* __restrict__ A,
                                                    const float* __restrict__ B2,
                                                    const int* __restrict__ rmap,
                                                    const short* __restrict__ Wt,
                                                    const float* __restrict__ bias,
                                                    float* __restrict__ out, int N) {
    __shared__ short As[64 * 32];   // [row][k] bf16, 4 KB
    __shared__ short Bs[128 * 32];  // [col][k] bf16, 8 KB
    const int tid = threadIdx.x;
    const int wv = tid >> 6, lane = tid & 63;
    const int lr = lane & 15, lg = lane >> 4;
    const int row0 = blockIdx.x * 64;

    // A-staging mapping: 4 threads/row, 8 f32 each
    const int arow = tid >> 2, apart = tid & 3;
    const int grow = row0 + arow;
    const int gr = grow < N ? grow : N - 1;
    const int rr = (K > 128) ? rmap[gr] : 0;
    // B-staging mapping: 2 threads/col, 16 bf16 each
    const int bc = tid & 127, bhalf = (tid >> 7) * 16;

    f32x4 acc[8];
#pragma unroll
    for (int t = 0; t < 8; ++t) acc[t] = (f32x4){0.f, 0.f, 0.f, 0.f};

#pragma unroll 1   // keep live ranges short (round-1 spill lesson)
    for (int kc = 0; kc < K / 32; ++kc) {
        const int k0 = kc * 32;
        // ---- stage A chunk: rows 0..63, k0..k0+31, f32 -> bf16, fused lrelu/concat ----
        {
            const int kbase = k0 + apart * 8;
            const float* sp;
            bool dolr;
            if (kbase < 128) { sp = A + (size_t)gr * 128 + kbase; dolr = LRA; }
            else             { sp = B2 + (size_t)rr * 128 + (kbase - 128); dolr = LRB; }
            float4 v0 = *(const float4*)sp;
            float4 v1 = *(const float4*)(sp + 4);
            float f[8] = {v0.x, v0.y, v0.z, v0.w, v1.x, v1.y, v1.z, v1.w};
            short8 pk;
#pragma unroll
            for (int j = 0; j < 8; ++j) {
                float x = f[j];
                if (dolr) x = lrelu(x);
                pk[j] = f2bf(x);
            }
            *(short8*)&As[arow * 32 + apart * 8] = pk;
        }
        // ---- stage B chunk: cols 0..127, k0..k0+31 from Wt (bf16, contiguous) ----
        {
            const short* wsrc = Wt + (size_t)bc * K + k0 + bhalf;
            *(short8*)&Bs[bc * 32 + bhalf]     = *(const short8*)wsrc;
            *(short8*)&Bs[bc * 32 + bhalf + 8] = *(const short8*)(wsrc + 8);
        }
        __syncthreads();
        // ---- fragments + MFMA: wave w does rows w*16..+16 x all 8 col-tiles ----
        short8 af = *(short8*)&As[(wv * 16 + lr) * 32 + lg * 8];
#pragma unroll
        for (int t = 0; t < 8; ++t) {
            short8 bf = *(short8*)&Bs[(t * 16 + lr) * 32 + lg * 8];
            acc[t] = __builtin_amdgcn_mfma_f32_16x16x32_bf16(af, bf, acc[t], 0, 0, 0);
        }
        __syncthreads();
    }

    // ---- epilogue: C/D layout col=lane&15, row=(lane>>4)*4+reg ----
#pragma unroll
    for (int t = 0; t < 8; ++t) {
#pragma unroll
        for (int r = 0; r < 4; ++r) {
            int grr = row0 + wv * 16 + lg * 4 + r;
            if (grr < N) {
                float v = acc[t][r];
                if (HASB) v += bias[t * 16 + lr];
                if (LROUT) v = lrelu(v);
                out[(size_t)grr * 128 + t * 16 + lr] = v;
            }
        }
    }
}

extern "C" void kernel_launch(void* const* d_in, const int* in_sizes, int n_in,
                              void* d_out, int out_size, void* d_ws, size_t ws_size,
                              hipStream_t stream) {
    const float* features = (const float*)d_in[0];
    const float* values   = (const float*)d_in[1];
    const float* W1 = (const float*)d_in[2];
    const float* b1 = (const float*)d_in[3];
    const float* W2 = (const float*)d_in[4];
    const float* b2 = (const float*)d_in[5];
    const float* Wl = (const float*)d_in[6];
    const float* bl = (const float*)d_in[7];
    const int* adjs     = (const int*)d_in[8];
    const int* root_idx = (const int*)d_in[9];
    const int* batch    = (const int*)d_in[12];
    float* out = (float*)d_out;

    const int N = in_sizes[0] / 128;
    const int E = in_sizes[1];
    const int* src = adjs;
    const int* dst = adjs + E;

    const size_t nf = (size_t)N * 128;
    float* bufA = (float*)d_ws;        // xw1 / xw2
    float* h1   = bufA + nf;           // conv1 output (+b1)
    float* h2   = h1 + nf;             // conv2 output (pre-lrelu, +b2)
    float* eval = h2 + nf;             // permuted edge weights [E]
    int*  esrc     = (int*)(eval + E); // permuted edge sources [E]
    int*  rmap     = esrc + E;         // node -> root-node index [N]
    int*  deg      = rmap + N;
    int*  rowstart = deg + N;          // [N+1]
    int*  cursor   = rowstart + N + 1;
    int*  chunksum = cursor + N;       // [128]
    int*  chunkoff = chunksum + 128;   // [128]
    uintptr_t wp = ((uintptr_t)(chunkoff + 128) + 15) & ~(uintptr_t)15;
    short* wt1 = (short*)wp;           // [128][128] bf16 (col-major of W1)
    short* wt2 = wt1 + 128 * 128;      // [128][256]
    short* wtl = wt2 + 256 * 128;      // [128][256]

    const int nchunks = (N + SCAN_CHUNK - 1) / SCAN_CHUNK;
    const int gblocks = (N + 63) / 64;

    // ---- CSR build + weight transpose (shared by both convs) ----
    zero_kernel<<<64, 256, 0, stream>>>(deg, N);
    rmap_kernel<<<64, 256, 0, stream>>>(batch, root_idx, rmap, N);
    wxpose_kernel<<<64, 256, 0, stream>>>(W1, wt1, 128);
    wxpose_kernel<<<128, 256, 0, stream>>>(W2, wt2, 256);
    wxpose_kernel<<<128, 256, 0, stream>>>(Wl, wtl, 256);
    count_kernel<<<1024, 256, 0, stream>>>(dst, deg, E);
    scan1_kernel<<<nchunks, 256, 0, stream>>>(deg, rowstart, chunksum, N);
    scan2_kernel<<<1, 64, 0, stream>>>(chunksum, chunkoff, nchunks, rowstart, N, E);
    scan3_kernel<<<64, 256, 0, stream>>>(rowstart, chunkoff, cursor, N);
    fill_kernel<<<1024, 256, 0, stream>>>(src, dst, values, cursor, esrc, eval, E);

    // ---- conv1: xw1 = features @ W1 ; h1 = b1 + gather ----
    mgemm_kernel<128, false, false, false, false>
        <<<gblocks, 256, 0, stream>>>(features, nullptr, nullptr, wt1, nullptr, bufA, N);
    gather_kernel<<<(N + 3) / 4, 256, 0, stream>>>(bufA, rowstart, esrc, eval, b1, h1, N);

    // ---- conv2: xw2 = concat(lrelu(h1), lrelu(features[root])) @ W2 ; h2 = b2 + gather ----
    mgemm_kernel<256, true, true, false, false>
        <<<gblocks, 256, 0, stream>>>(h1, features, rmap, wt2, nullptr, bufA, N);
    gather_kernel<<<(N + 3) / 4, 256, 0, stream>>>(bufA, rowstart, esrc, eval, b2, h2, N);

    // ---- out = lrelu( concat(lrelu(h2), h1[root]) @ Wl + bl ) ----
    mgemm_kernel<256, true, false, true, true>
        <<<gblocks, 256, 0, stream>>>(h2, h1, rmap, wtl, bl, out, N);
}

// Round 6
// 317.688 us; speedup vs baseline: 52.7244x; 1.2081x over previous
//
#include <hip/hip_runtime.h>
#include <hip/hip_bf16.h>

#define NEG_SLOPE 0.01f
#define SCAN_CHUNK 1024

typedef __attribute__((ext_vector_type(8))) short short8;
typedef __attribute__((ext_vector_type(4))) float f32x4;

__device__ __forceinline__ float lrelu(float x) { return x > 0.f ? x : NEG_SLOPE * x; }

// f32 -> bf16 bits, round-to-nearest-even
__device__ __forceinline__ unsigned short f2bf(float f) {
    unsigned u = __builtin_bit_cast(unsigned, f);
    u += 0x7fffu + ((u >> 16) & 1u);
    return (unsigned short)(u >> 16);
}
__device__ __forceinline__ float bf2f(unsigned short h) {
    return __builtin_bit_cast(float, (unsigned)h << 16);
}
__device__ __forceinline__ float bflo(unsigned u) {
    return __builtin_bit_cast(float, u << 16);
}
__device__ __forceinline__ float bfhi(unsigned u) {
    return __builtin_bit_cast(float, u & 0xffff0000u);
}

// Fused prep: feat16 = bf16(features); rmap; deg=0; wt1/wt2/wtl transposed bf16 weights.
__global__ __launch_bounds__(256) void prep_kernel(
        const float* __restrict__ features, const int* __restrict__ batch,
        const int* __restrict__ root_idx, const float* __restrict__ W1,
        const float* __restrict__ W2, const float* __restrict__ Wl,
        unsigned short* __restrict__ feat16, int* __restrict__ rmap,
        int* __restrict__ deg, unsigned short* __restrict__ wt1,
        unsigned short* __restrict__ wt2, unsigned short* __restrict__ wtl, int N) {
    const int total = N * 32;  // float4 groups of features
    for (int i = blockIdx.x * blockDim.x + threadIdx.x; i < total;
         i += gridDim.x * blockDim.x) {
        float4 v = *(const float4*)(features + (size_t)i * 4);
        ushort4 p;
        p.x = f2bf(v.x); p.y = f2bf(v.y); p.z = f2bf(v.z); p.w = f2bf(v.w);
        *(ushort4*)(feat16 + (size_t)i * 4) = p;
        if (i < N) { rmap[i] = root_idx[batch[i]]; deg[i] = 0; }
        if (i < 128 * 128) {
            int k = i >> 7, c = i & 127;
            wt1[c * 128 + k] = f2bf(W1[i]);
        }
        if (i < 256 * 128) {
            int k = i >> 7, c = i & 127;
            wt2[c * 256 + k] = f2bf(W2[i]);
            wtl[c * 256 + k] = f2bf(Wl[i]);
        }
    }
}

// deg[dst[e]]++
__global__ void count_kernel(const int* __restrict__ dst, int* __restrict__ deg, int E) {
    for (int e = blockIdx.x * blockDim.x + threadIdx.x; e < E; e += gridDim.x * blockDim.x)
        atomicAdd(&deg[dst[e]], 1);
}

__global__ __launch_bounds__(256) void scan1_kernel(const int* __restrict__ deg,
                                                    int* __restrict__ rowstart,
                                                    int* __restrict__ chunksum, int N) {
    __shared__ int ts[256];
    const int b = blockIdx.x, t = threadIdx.x;
    const int base = b * SCAN_CHUNK + t * 4;
    int v[4], s = 0;
#pragma unroll
    for (int j = 0; j < 4; ++j) {
        v[j] = (base + j < N) ? deg[base + j] : 0;
        s += v[j];
    }
    ts[t] = s;
    __syncthreads();
    for (int off = 1; off < 256; off <<= 1) {
        int x = (t >= off) ? ts[t - off] : 0;
        __syncthreads();
        ts[t] += x;
        __syncthreads();
    }
    int run = ts[t] - s;
#pragma unroll
    for (int j = 0; j < 4; ++j) {
        if (base + j < N) rowstart[base + j] = run;
        run += v[j];
    }
    if (t == 255) chunksum[b] = ts[255];
}

__global__ void scan2_kernel(const int* __restrict__ chunksum, int* __restrict__ chunkoff,
                             int nchunks, int* __restrict__ rowstart, int N, int E) {
    if (blockIdx.x == 0 && threadIdx.x == 0) {
        int acc = 0;
        for (int i = 0; i < nchunks; ++i) { chunkoff[i] = acc; acc += chunksum[i]; }
        rowstart[N] = E;
    }
}

__global__ void scan3_kernel(int* __restrict__ rowstart, const int* __restrict__ chunkoff,
                             int* __restrict__ cursor, int N) {
    for (int i = blockIdx.x * blockDim.x + threadIdx.x; i < N; i += gridDim.x * blockDim.x) {
        int v = rowstart[i] + chunkoff[i / SCAN_CHUNK];
        rowstart[i] = v;
        cursor[i] = v;
    }
}

__global__ void fill_kernel(const int* __restrict__ src, const int* __restrict__ dst,
                            const float* __restrict__ vals, int* __restrict__ cursor,
                            int* __restrict__ esrc, float* __restrict__ eval, int E) {
    for (int e = blockIdx.x * blockDim.x + threadIdx.x; e < E; e += gridDim.x * blockDim.x) {
        int d = dst[e];
        int pos = atomicAdd(&cursor[d], 1);
        esrc[pos] = src[e];
        eval[pos] = vals[e];
    }
}

// h[i] = bf16( bias + sum_{e in CSR[i]} eval[e] * xw[esrc[e]] )  (one wave per node, xw bf16)
__global__ __launch_bounds__(256) void gather_kernel(const unsigned short* __restrict__ xw,
                                                     const int* __restrict__ rowstart,
                                                     const int* __restrict__ esrc,
                                                     const float* __restrict__ eval,
                                                     const float* __restrict__ bias,
                                                     unsigned short* __restrict__ h, int N) {
    const int node = blockIdx.x * 4 + (threadIdx.x >> 6);
    const int lane = threadIdx.x & 63;
    if (node >= N) return;
    const int s0 = rowstart[node], s1 = rowstart[node + 1];
    float2 acc = *(const float2*)(bias + lane * 2);
    int e = s0;
    for (; e + 4 <= s1; e += 4) {
        int sa = esrc[e], sb = esrc[e + 1], sc = esrc[e + 2], sd = esrc[e + 3];
        float va = eval[e], vb = eval[e + 1], vc = eval[e + 2], vd = eval[e + 3];
        unsigned xa = *(const unsigned*)(xw + (size_t)sa * 128 + lane * 2);
        unsigned xb = *(const unsigned*)(xw + (size_t)sb * 128 + lane * 2);
        unsigned xc = *(const unsigned*)(xw + (size_t)sc * 128 + lane * 2);
        unsigned xd = *(const unsigned*)(xw + (size_t)sd * 128 + lane * 2);
        acc.x = fmaf(va, bflo(xa), acc.x);
        acc.y = fmaf(va, bfhi(xa), acc.y);
        acc.x = fmaf(vb, bflo(xb), acc.x);
        acc.y = fmaf(vb, bfhi(xb), acc.y);
        acc.x = fmaf(vc, bflo(xc), acc.x);
        acc.y = fmaf(vc, bfhi(xc), acc.y);
        acc.x = fmaf(vd, bflo(xd), acc.x);
        acc.y = fmaf(vd, bfhi(xd), acc.y);
    }
    for (; e < s1; ++e) {
        int sa = esrc[e];
        float va = eval[e];
        unsigned xa = *(const unsigned*)(xw + (size_t)sa * 128 + lane * 2);
        acc.x = fmaf(va, bflo(xa), acc.x);
        acc.y = fmaf(va, bfhi(xa), acc.y);
    }
    unsigned pk = (unsigned)f2bf(acc.x) | ((unsigned)f2bf(acc.y) << 16);
    *(unsigned*)(h + (size_t)node * 128 + lane * 2) = pk;
}

// MFMA GEMM: out[N,128] = act( concat(actA(A), actB(B2[rmap])) @ W (+bias) )
// A, B2 bf16; Wt pre-transposed bf16 Wt[c*K+k]. 64 rows/block, 4 waves.
template <int K, bool LRA, bool LRB, bool LROUT, bool HASB, bool OUTBF>
__global__ __launch_bounds__(256) void mgemm_kernel(const unsigned short* __restrict__ A,
                                                    const unsigned short* __restrict__ B2,
                                                    const int* __restrict__ rmap,
                                                    const unsigned short* __restrict__ Wt,
                                                    const float* __restrict__ bias,
                                                    void* __restrict__ outv, int N) {
    __shared__ short As[64 * 32];   // [row][k] bf16, 4 KB
    __shared__ short Bs[128 * 32];  // [col][k] bf16, 8 KB
    const int tid = threadIdx.x;
    const int wv = tid >> 6, lane = tid & 63;
    const int lr = lane & 15, lg = lane >> 4;
    const int row0 = blockIdx.x * 64;

    // A-staging: 4 threads/row, 8 bf16 each (16 B)
    const int arow = tid >> 2, apart = tid & 3;
    const int grow = row0 + arow;
    const int gr = grow < N ? grow : N - 1;
    const int rr = (K > 128) ? rmap[gr] : 0;
    // B-staging: 2 threads/col, 16 bf16 each
    const int bc = tid & 127, bhalf = (tid >> 7) * 16;

    f32x4 acc[8];
#pragma unroll
    for (int t = 0; t < 8; ++t) acc[t] = (f32x4){0.f, 0.f, 0.f, 0.f};

#pragma unroll 1   // keep live ranges short (round-1 spill lesson)
    for (int kc = 0; kc < K / 32; ++kc) {
        const int k0 = kc * 32;
        // ---- stage A chunk (bf16, fused lrelu/concat) ----
        {
            const int kbase = k0 + apart * 8;
            const bool inA = kbase < 128;
            const unsigned short* sp = inA ? A + (size_t)gr * 128 + kbase
                                           : B2 + (size_t)rr * 128 + (kbase - 128);
            short8 v = *(const short8*)sp;
            const bool dolr = inA ? LRA : LRB;
            if (dolr) {
#pragma unroll
                for (int j = 0; j < 8; ++j)
                    v[j] = (short)f2bf(lrelu(bf2f((unsigned short)v[j])));
            }
            *(short8*)&As[arow * 32 + apart * 8] = v;
        }
        // ---- stage B chunk from Wt ----
        {
            const unsigned short* wsrc = Wt + (size_t)bc * K + k0 + bhalf;
            *(short8*)&Bs[bc * 32 + bhalf]     = *(const short8*)wsrc;
            *(short8*)&Bs[bc * 32 + bhalf + 8] = *(const short8*)(wsrc + 8);
        }
        __syncthreads();
        // ---- MFMA: wave wv does rows wv*16..+16 x 8 col-tiles ----
        short8 af = *(short8*)&As[(wv * 16 + lr) * 32 + lg * 8];
#pragma unroll
        for (int t = 0; t < 8; ++t) {
            short8 bf = *(short8*)&Bs[(t * 16 + lr) * 32 + lg * 8];
            acc[t] = __builtin_amdgcn_mfma_f32_16x16x32_bf16(af, bf, acc[t], 0, 0, 0);
        }
        __syncthreads();
    }

    // ---- epilogue: C/D layout col=lane&15, row=(lane>>4)*4+reg ----
#pragma unroll
    for (int t = 0; t < 8; ++t) {
#pragma unroll
        for (int r = 0; r < 4; ++r) {
            int grr = row0 + wv * 16 + lg * 4 + r;
            if (grr < N) {
                float v = acc[t][r];
                if (HASB) v += bias[t * 16 + lr];
                if (LROUT) v = lrelu(v);
                if (OUTBF)
                    ((unsigned short*)outv)[(size_t)grr * 128 + t * 16 + lr] = f2bf(v);
                else
                    ((float*)outv)[(size_t)grr * 128 + t * 16 + lr] = v;
            }
        }
    }
}

extern "C" void kernel_launch(void* const* d_in, const int* in_sizes, int n_in,
                              void* d_out, int out_size, void* d_ws, size_t ws_size,
                              hipStream_t stream) {
    const float* features = (const float*)d_in[0];
    const float* values   = (const float*)d_in[1];
    const float* W1 = (const float*)d_in[2];
    const float* b1 = (const float*)d_in[3];
    const float* W2 = (const float*)d_in[4];
    const float* b2 = (const float*)d_in[5];
    const float* Wl = (const float*)d_in[6];
    const float* bl = (const float*)d_in[7];
    const int* adjs     = (const int*)d_in[8];
    const int* root_idx = (const int*)d_in[9];
    const int* batch    = (const int*)d_in[12];
    float* out = (float*)d_out;

    const int N = in_sizes[0] / 128;
    const int E = in_sizes[1];
    const int* src = adjs;
    const int* dst = adjs + E;

    const size_t nf = (size_t)N * 128;
    unsigned short* bufA   = (unsigned short*)d_ws;  // xw1/xw2 bf16 [N*128]
    unsigned short* h1     = bufA + nf;              // conv1 out bf16 (raw, +b1)
    unsigned short* h2     = h1 + nf;                // conv2 out bf16 (pre-lrelu, +b2)
    unsigned short* feat16 = h2 + nf;                // bf16 features
    unsigned short* wt1 = feat16 + nf;               // [128][128]
    unsigned short* wt2 = wt1 + 128 * 128;           // [128][256]
    unsigned short* wtl = wt2 + 256 * 128;           // [128][256]
    float* eval    = (float*)(wtl + 256 * 128);      // permuted edge weights [E]
    int*  esrc     = (int*)(eval + E);               // permuted edge sources [E]
    int*  rmap     = esrc + E;
    int*  deg      = rmap + N;
    int*  rowstart = deg + N;                        // [N+1]
    int*  cursor   = rowstart + N + 1;
    int*  chunksum = cursor + N;                     // [128]
    int*  chunkoff = chunksum + 128;                 // [128]

    const int nchunks = (N + SCAN_CHUNK - 1) / SCAN_CHUNK;
    const int gblocks = (N + 63) / 64;

    // ---- prep (feat16, rmap, deg=0, weight transposes) + CSR build ----
    prep_kernel<<<1024, 256, 0, stream>>>(features, batch, root_idx, W1, W2, Wl,
                                          feat16, rmap, deg, wt1, wt2, wtl, N);
    count_kernel<<<1024, 256, 0, stream>>>(dst, deg, E);
    scan1_kernel<<<nchunks, 256, 0, stream>>>(deg, rowstart, chunksum, N);
    scan2_kernel<<<1, 64, 0, stream>>>(chunksum, chunkoff, nchunks, rowstart, N, E);
    scan3_kernel<<<64, 256, 0, stream>>>(rowstart, chunkoff, cursor, N);
    fill_kernel<<<1024, 256, 0, stream>>>(src, dst, values, cursor, esrc, eval, E);

    // ---- conv1: xw1 = feat16 @ W1 ; h1 = bf16(b1 + gather) ----
    mgemm_kernel<128, false, false, false, false, true>
        <<<gblocks, 256, 0, stream>>>(feat16, nullptr, nullptr, wt1, nullptr, bufA, N);
    gather_kernel<<<(N + 3) / 4, 256, 0, stream>>>(bufA, rowstart, esrc, eval, b1, h1, N);

    // ---- conv2: xw2 = concat(lrelu(h1), lrelu(feat16[root])) @ W2 ; h2 = bf16(b2 + gather) ----
    mgemm_kernel<256, true, true, false, false, true>
        <<<gblocks, 256, 0, stream>>>(h1, feat16, rmap, wt2, nullptr, bufA, N);
    gather_kernel<<<(N + 3) / 4, 256, 0, stream>>>(bufA, rowstart, esrc, eval, b2, h2, N);

    // ---- out = lrelu( concat(lrelu(h2), h1[root]) @ Wl + bl )  (f32 out) ----
    mgemm_kernel<256, true, false, true, true, false>
        <<<gblocks, 256, 0, stream>>>(h2, h1, rmap, wtl, bl, out, N);
}

// Round 7
// 311.557 us; speedup vs baseline: 53.7619x; 1.0197x over previous
//
#include <hip/hip_runtime.h>
#include <hip/hip_bf16.h>

#define NEG_SLOPE 0.01f
#define SCAN_CHUNK 1024

typedef __attribute__((ext_vector_type(8))) short short8;
typedef __attribute__((ext_vector_type(4))) float f32x4;

__device__ __forceinline__ float lrelu(float x) { return x > 0.f ? x : NEG_SLOPE * x; }

// f32 -> bf16 bits, round-to-nearest-even
__device__ __forceinline__ unsigned short f2bf(float f) {
    unsigned u = __builtin_bit_cast(unsigned, f);
    u += 0x7fffu + ((u >> 16) & 1u);
    return (unsigned short)(u >> 16);
}
__device__ __forceinline__ float bf2f(unsigned short h) {
    return __builtin_bit_cast(float, (unsigned)h << 16);
}
__device__ __forceinline__ float bflo(unsigned u) {
    return __builtin_bit_cast(float, u << 16);
}
__device__ __forceinline__ float bfhi(unsigned u) {
    return __builtin_bit_cast(float, u & 0xffff0000u);
}

// Fused prep: feat16 = bf16(features); rmap; deg=0; wt1/wt2/wtl transposed bf16 weights.
__global__ __launch_bounds__(256) void prep_kernel(
        const float* __restrict__ features, const int* __restrict__ batch,
        const int* __restrict__ root_idx, const float* __restrict__ W1,
        const float* __restrict__ W2, const float* __restrict__ Wl,
        unsigned short* __restrict__ feat16, int* __restrict__ rmap,
        int* __restrict__ deg, unsigned short* __restrict__ wt1,
        unsigned short* __restrict__ wt2, unsigned short* __restrict__ wtl, int N) {
    const int total = N * 32;  // float4 groups of features
    for (int i = blockIdx.x * blockDim.x + threadIdx.x; i < total;
         i += gridDim.x * blockDim.x) {
        float4 v = *(const float4*)(features + (size_t)i * 4);
        ushort4 p;
        p.x = f2bf(v.x); p.y = f2bf(v.y); p.z = f2bf(v.z); p.w = f2bf(v.w);
        *(ushort4*)(feat16 + (size_t)i * 4) = p;
        if (i < N) { rmap[i] = root_idx[batch[i]]; deg[i] = 0; }
        if (i < 128 * 128) {
            int k = i >> 7, c = i & 127;
            wt1[c * 128 + k] = f2bf(W1[i]);
        }
        if (i < 256 * 128) {
            int k = i >> 7, c = i & 127;
            wt2[c * 256 + k] = f2bf(W2[i]);
            wtl[c * 256 + k] = f2bf(Wl[i]);
        }
    }
}

// deg[dst[e]]++  (4 edges/thread, vector loads)
__global__ void count_kernel(const int* __restrict__ dst, int* __restrict__ deg, int E) {
    const int stride = gridDim.x * blockDim.x;
    const int i = blockIdx.x * blockDim.x + threadIdx.x;
    const int e4 = E >> 2;
    for (int q = i; q < e4; q += stride) {
        int4 d = ((const int4*)dst)[q];
        atomicAdd(&deg[d.x], 1);
        atomicAdd(&deg[d.y], 1);
        atomicAdd(&deg[d.z], 1);
        atomicAdd(&deg[d.w], 1);
    }
    for (int e = e4 * 4 + i; e < E; e += stride) atomicAdd(&deg[dst[e]], 1);
}

__global__ __launch_bounds__(256) void scan1_kernel(const int* __restrict__ deg,
                                                    int* __restrict__ rowstart,
                                                    int* __restrict__ chunksum, int N) {
    __shared__ int ts[256];
    const int b = blockIdx.x, t = threadIdx.x;
    const int base = b * SCAN_CHUNK + t * 4;
    int v[4], s = 0;
#pragma unroll
    for (int j = 0; j < 4; ++j) {
        v[j] = (base + j < N) ? deg[base + j] : 0;
        s += v[j];
    }
    ts[t] = s;
    __syncthreads();
    for (int off = 1; off < 256; off <<= 1) {
        int x = (t >= off) ? ts[t - off] : 0;
        __syncthreads();
        ts[t] += x;
        __syncthreads();
    }
    int run = ts[t] - s;
#pragma unroll
    for (int j = 0; j < 4; ++j) {
        if (base + j < N) rowstart[base + j] = run;
        run += v[j];
    }
    if (t == 255) chunksum[b] = ts[255];
}

__global__ void scan2_kernel(const int* __restrict__ chunksum, int* __restrict__ chunkoff,
                             int nchunks, int* __restrict__ rowstart, int N, int E) {
    if (blockIdx.x == 0 && threadIdx.x == 0) {
        int acc = 0;
        for (int i = 0; i < nchunks; ++i) { chunkoff[i] = acc; acc += chunksum[i]; }
        rowstart[N] = E;
    }
}

__global__ void scan3_kernel(int* __restrict__ rowstart, const int* __restrict__ chunkoff,
                             int* __restrict__ cursor, int N) {
    for (int i = blockIdx.x * blockDim.x + threadIdx.x; i < N; i += gridDim.x * blockDim.x) {
        int v = rowstart[i] + chunkoff[i / SCAN_CHUNK];
        rowstart[i] = v;
        cursor[i] = v;
    }
}

// counting-sort edges by dst into combined records edata[pos] = {src, val-bits}
__global__ void fill_kernel(const int* __restrict__ src, const int* __restrict__ dst,
                            const float* __restrict__ vals, int* __restrict__ cursor,
                            int2* __restrict__ edata, int E) {
    const int stride = gridDim.x * blockDim.x;
    const int i = blockIdx.x * blockDim.x + threadIdx.x;
    const int e4 = E >> 2;
    for (int q = i; q < e4; q += stride) {
        int4 s = ((const int4*)src)[q];
        int4 d = ((const int4*)dst)[q];
        float4 v = ((const float4*)vals)[q];
        int p;
        p = atomicAdd(&cursor[d.x], 1);
        edata[p] = make_int2(s.x, __builtin_bit_cast(int, v.x));
        p = atomicAdd(&cursor[d.y], 1);
        edata[p] = make_int2(s.y, __builtin_bit_cast(int, v.y));
        p = atomicAdd(&cursor[d.z], 1);
        edata[p] = make_int2(s.z, __builtin_bit_cast(int, v.z));
        p = atomicAdd(&cursor[d.w], 1);
        edata[p] = make_int2(s.w, __builtin_bit_cast(int, v.w));
    }
    for (int e = e4 * 4 + i; e < E; e += stride) {
        int p = atomicAdd(&cursor[dst[e]], 1);
        edata[p] = make_int2(src[e], __builtin_bit_cast(int, vals[e]));
    }
}

// h[i] = bf16( bias + sum_{e in CSR[i]} val_e * xw[src_e] )  (one wave per node, xw bf16)
__global__ __launch_bounds__(256) void gather_kernel(const unsigned short* __restrict__ xw,
                                                     const int* __restrict__ rowstart,
                                                     const int2* __restrict__ edata,
                                                     const float* __restrict__ bias,
                                                     unsigned short* __restrict__ h, int N) {
    const int node = blockIdx.x * 4 + (threadIdx.x >> 6);
    const int lane = threadIdx.x & 63;
    if (node >= N) return;
    const int s0 = rowstart[node], s1 = rowstart[node + 1];
    float2 acc = *(const float2*)(bias + lane * 2);
    int e = s0;
    for (; e + 4 <= s1; e += 4) {
        int2 e0 = edata[e], e1 = edata[e + 1], e2 = edata[e + 2], e3 = edata[e + 3];
        unsigned xa = *(const unsigned*)(xw + (size_t)e0.x * 128 + lane * 2);
        unsigned xb = *(const unsigned*)(xw + (size_t)e1.x * 128 + lane * 2);
        unsigned xc = *(const unsigned*)(xw + (size_t)e2.x * 128 + lane * 2);
        unsigned xd = *(const unsigned*)(xw + (size_t)e3.x * 128 + lane * 2);
        float va = __builtin_bit_cast(float, e0.y), vb = __builtin_bit_cast(float, e1.y);
        float vc = __builtin_bit_cast(float, e2.y), vd = __builtin_bit_cast(float, e3.y);
        acc.x = fmaf(va, bflo(xa), acc.x);
        acc.y = fmaf(va, bfhi(xa), acc.y);
        acc.x = fmaf(vb, bflo(xb), acc.x);
        acc.y = fmaf(vb, bfhi(xb), acc.y);
        acc.x = fmaf(vc, bflo(xc), acc.x);
        acc.y = fmaf(vc, bfhi(xc), acc.y);
        acc.x = fmaf(vd, bflo(xd), acc.x);
        acc.y = fmaf(vd, bfhi(xd), acc.y);
    }
    for (; e < s1; ++e) {
        int2 e0 = edata[e];
        float va = __builtin_bit_cast(float, e0.y);
        unsigned xa = *(const unsigned*)(xw + (size_t)e0.x * 128 + lane * 2);
        acc.x = fmaf(va, bflo(xa), acc.x);
        acc.y = fmaf(va, bfhi(xa), acc.y);
    }
    unsigned pk = (unsigned)f2bf(acc.x) | ((unsigned)f2bf(acc.y) << 16);
    *(unsigned*)(h + (size_t)node * 128 + lane * 2) = pk;
}

// MFMA GEMM: out[N,128] = act( concat(actA(A), actB(B2[rmap])) @ W (+bias) )
// A, B2 bf16; Wt pre-transposed bf16 Wt[c*K+k]. 64 rows/block, 4 waves.
template <int K, bool LRA, bool LRB, bool LROUT, bool HASB, bool OUTBF>
__global__ __launch_bounds__(256) void mgemm_kernel(const unsigned short* __restrict__ A,
                                                    const unsigned short* __restrict__ B2,
                                                    const int* __restrict__ rmap,
                                                    const unsigned short* __restrict__ Wt,
                                                    const float* __restrict__ bias,
                                                    void* __restrict__ outv, int N) {
    __shared__ short As[64 * 32];   // [row][k] bf16, 4 KB
    __shared__ short Bs[128 * 32];  // [col][k] bf16, 8 KB
    const int tid = threadIdx.x;
    const int wv = tid >> 6, lane = tid & 63;
    const int lr = lane & 15, lg = lane >> 4;
    const int row0 = blockIdx.x * 64;

    // A-staging: 4 threads/row, 8 bf16 each (16 B)
    const int arow = tid >> 2, apart = tid & 3;
    const int grow = row0 + arow;
    const int gr = grow < N ? grow : N - 1;
    const int rr = (K > 128) ? rmap[gr] : 0;
    // B-staging: 2 threads/col, 16 bf16 each
    const int bc = tid & 127, bhalf = (tid >> 7) * 16;

    f32x4 acc[8];
#pragma unroll
    for (int t = 0; t < 8; ++t) acc[t] = (f32x4){0.f, 0.f, 0.f, 0.f};

#pragma unroll 1   // keep live ranges short (round-1 spill lesson)
    for (int kc = 0; kc < K / 32; ++kc) {
        const int k0 = kc * 32;
        // ---- stage A chunk (bf16, fused lrelu/concat) ----
        {
            const int kbase = k0 + apart * 8;
            const bool inA = kbase < 128;
            const unsigned short* sp = inA ? A + (size_t)gr * 128 + kbase
                                           : B2 + (size_t)rr * 128 + (kbase - 128);
            short8 v = *(const short8*)sp;
            const bool dolr = inA ? LRA : LRB;
            if (dolr) {
#pragma unroll
                for (int j = 0; j < 8; ++j)
                    v[j] = (short)f2bf(lrelu(bf2f((unsigned short)v[j])));
            }
            *(short8*)&As[arow * 32 + apart * 8] = v;
        }
        // ---- stage B chunk from Wt ----
        {
            const unsigned short* wsrc = Wt + (size_t)bc * K + k0 + bhalf;
            *(short8*)&Bs[bc * 32 + bhalf]     = *(const short8*)wsrc;
            *(short8*)&Bs[bc * 32 + bhalf + 8] = *(const short8*)(wsrc + 8);
        }
        __syncthreads();
        // ---- MFMA: wave wv does rows wv*16..+16 x 8 col-tiles ----
        short8 af = *(short8*)&As[(wv * 16 + lr) * 32 + lg * 8];
#pragma unroll
        for (int t = 0; t < 8; ++t) {
            short8 bf = *(short8*)&Bs[(t * 16 + lr) * 32 + lg * 8];
            acc[t] = __builtin_amdgcn_mfma_f32_16x16x32_bf16(af, bf, acc[t], 0, 0, 0);
        }
        __syncthreads();
    }

    // ---- epilogue: C/D layout col=lane&15, row=(lane>>4)*4+reg ----
#pragma unroll
    for (int t = 0; t < 8; ++t) {
#pragma unroll
        for (int r = 0; r < 4; ++r) {
            int grr = row0 + wv * 16 + lg * 4 + r;
            if (grr < N) {
                float v = acc[t][r];
                if (HASB) v += bias[t * 16 + lr];
                if (LROUT) v = lrelu(v);
                if (OUTBF)
                    ((unsigned short*)outv)[(size_t)grr * 128 + t * 16 + lr] = f2bf(v);
                else
                    ((float*)outv)[(size_t)grr * 128 + t * 16 + lr] = v;
            }
        }
    }
}

extern "C" void kernel_launch(void* const* d_in, const int* in_sizes, int n_in,
                              void* d_out, int out_size, void* d_ws, size_t ws_size,
                              hipStream_t stream) {
    const float* features = (const float*)d_in[0];
    const float* values   = (const float*)d_in[1];
    const float* W1 = (const float*)d_in[2];
    const float* b1 = (const float*)d_in[3];
    const float* W2 = (const float*)d_in[4];
    const float* b2 = (const float*)d_in[5];
    const float* Wl = (const float*)d_in[6];
    const float* bl = (const float*)d_in[7];
    const int* adjs     = (const int*)d_in[8];
    const int* root_idx = (const int*)d_in[9];
    const int* batch    = (const int*)d_in[12];
    float* out = (float*)d_out;

    const int N = in_sizes[0] / 128;
    const int E = in_sizes[1];
    const int* src = adjs;
    const int* dst = adjs + E;

    const size_t nf = (size_t)N * 128;
    unsigned short* bufA   = (unsigned short*)d_ws;  // xw1/xw2 bf16 [N*128]
    unsigned short* h1     = bufA + nf;              // conv1 out bf16 (raw, +b1)
    unsigned short* h2     = h1 + nf;                // conv2 out bf16 (pre-lrelu, +b2)
    unsigned short* feat16 = h2 + nf;                // bf16 features
    unsigned short* wt1 = feat16 + nf;               // [128][128]
    unsigned short* wt2 = wt1 + 128 * 128;           // [128][256]
    unsigned short* wtl = wt2 + 256 * 128;           // [128][256]
    uintptr_t ep = ((uintptr_t)(wtl + 256 * 128) + 7) & ~(uintptr_t)7;
    int2* edata    = (int2*)ep;                      // combined {src, val} records [E]
    int*  rmap     = (int*)(edata + E);
    int*  deg      = rmap + N;
    int*  rowstart = deg + N;                        // [N+1]
    int*  cursor   = rowstart + N + 1;
    int*  chunksum = cursor + N;                     // [128]
    int*  chunkoff = chunksum + 128;                 // [128]

    const int nchunks = (N + SCAN_CHUNK - 1) / SCAN_CHUNK;
    const int gblocks = (N + 63) / 64;

    // ---- prep (feat16, rmap, deg=0, weight transposes) + CSR build ----
    prep_kernel<<<1024, 256, 0, stream>>>(features, batch, root_idx, W1, W2, Wl,
                                          feat16, rmap, deg, wt1, wt2, wtl, N);
    count_kernel<<<512, 256, 0, stream>>>(dst, deg, E);
    scan1_kernel<<<nchunks, 256, 0, stream>>>(deg, rowstart, chunksum, N);
    scan2_kernel<<<1, 64, 0, stream>>>(chunksum, chunkoff, nchunks, rowstart, N, E);
    scan3_kernel<<<64, 256, 0, stream>>>(rowstart, chunkoff, cursor, N);
    fill_kernel<<<512, 256, 0, stream>>>(src, dst, values, cursor, edata, E);

    // ---- conv1: xw1 = feat16 @ W1 ; h1 = bf16(b1 + gather) ----
    mgemm_kernel<128, false, false, false, false, true>
        <<<gblocks, 256, 0, stream>>>(feat16, nullptr, nullptr, wt1, nullptr, bufA, N);
    gather_kernel<<<(N + 3) / 4, 256, 0, stream>>>(bufA, rowstart, edata, b1, h1, N);

    // ---- conv2: xw2 = concat(lrelu(h1), lrelu(feat16[root])) @ W2 ; h2 = bf16(b2 + gather) ----
    mgemm_kernel<256, true, true, false, false, true>
        <<<gblocks, 256, 0, stream>>>(h1, feat16, rmap, wt2, nullptr, bufA, N);
    gather_kernel<<<(N + 3) / 4, 256, 0, stream>>>(bufA, rowstart, edata, b2, h2, N);

    // ---- out = lrelu( concat(lrelu(h2), h1[root]) @ Wl + bl )  (f32 out) ----
    mgemm_kernel<256, true, false, true, true, false>
        <<<gblocks, 256, 0, stream>>>(h2, h1, rmap, wtl, bl, out, N);
}

// Round 9
// 272.952 us; speedup vs baseline: 61.3657x; 1.1414x over previous
//
#include <hip/hip_runtime.h>
#include <hip/hip_bf16.h>

#define NEG_SLOPE 0.01f
#define NBUK_MAX 256
#define ATILE 2048

typedef __attribute__((ext_vector_type(8))) short short8;
typedef __attribute__((ext_vector_type(4))) float f32x4;

__device__ __forceinline__ float lrelu(float x) { return x > 0.f ? x : NEG_SLOPE * x; }

// f32 -> bf16 bits, round-to-nearest-even
__device__ __forceinline__ unsigned short f2bf(float f) {
    unsigned u = __builtin_bit_cast(unsigned, f);
    u += 0x7fffu + ((u >> 16) & 1u);
    return (unsigned short)(u >> 16);
}
__device__ __forceinline__ float bf2f(unsigned short h) {
    return __builtin_bit_cast(float, (unsigned)h << 16);
}
__device__ __forceinline__ float bflo(unsigned u) {
    return __builtin_bit_cast(float, u << 16);
}
__device__ __forceinline__ float bfhi(unsigned u) {
    return __builtin_bit_cast(float, u & 0xffff0000u);
}

// Fused prep: feat16 = bf16(features); rmap; bucket_count=0; transposed bf16 weights.
__global__ __launch_bounds__(256) void prep_kernel(
        const float* __restrict__ features, const int* __restrict__ batch,
        const int* __restrict__ root_idx, const float* __restrict__ W1,
        const float* __restrict__ W2, const float* __restrict__ Wl,
        unsigned short* __restrict__ feat16, int* __restrict__ rmap,
        int* __restrict__ bucket_count, unsigned short* __restrict__ wt1,
        unsigned short* __restrict__ wt2, unsigned short* __restrict__ wtl,
        int N, int nbuk) {
    const int total = N * 32;  // float4 groups of features
    for (int i = blockIdx.x * blockDim.x + threadIdx.x; i < total;
         i += gridDim.x * blockDim.x) {
        float4 v = *(const float4*)(features + (size_t)i * 4);
        ushort4 p;
        p.x = f2bf(v.x); p.y = f2bf(v.y); p.z = f2bf(v.z); p.w = f2bf(v.w);
        *(ushort4*)(feat16 + (size_t)i * 4) = p;
        if (i < N) rmap[i] = root_idx[batch[i]];
        if (i < nbuk) bucket_count[i] = 0;
        if (i < 128 * 128) {
            int k = i >> 7, c = i & 127;
            wt1[c * 128 + k] = f2bf(W1[i]);
        }
        if (i < 256 * 128) {
            int k = i >> 7, c = i & 127;
            wt2[c * 256 + k] = f2bf(W2[i]);
            wtl[c * 256 + k] = f2bf(Wl[i]);
        }
    }
}

// A1: coarse histogram of dst>>8 (LDS-aggregated)
__global__ __launch_bounds__(256) void histA_kernel(const int* __restrict__ dst,
                                                    int* __restrict__ bucket_count,
                                                    int E, int nbuk) {
    __shared__ int hist[NBUK_MAX];
    if (threadIdx.x < nbuk) hist[threadIdx.x] = 0;
    __syncthreads();
    for (int e = blockIdx.x * blockDim.x + threadIdx.x; e < E; e += gridDim.x * blockDim.x)
        atomicAdd(&hist[dst[e] >> 8], 1);
    __syncthreads();
    if (threadIdx.x < nbuk) {
        int v = hist[threadIdx.x];
        if (v) atomicAdd(&bucket_count[threadIdx.x], v);
    }
}

// A2: scan bucket counts -> bucket_base/cursor; rowstart[N]=E
__global__ __launch_bounds__(256) void scanA_kernel(const int* __restrict__ bucket_count,
                                                    int* __restrict__ bucket_base,
                                                    int* __restrict__ bucket_cursor,
                                                    int* __restrict__ rowstart,
                                                    int N, int E, int nbuk) {
    __shared__ int sb[256];
    const int t = threadIdx.x;
    int v = (t < nbuk) ? bucket_count[t] : 0;
    sb[t] = v;
    __syncthreads();
    for (int off = 1; off < 256; off <<= 1) {
        int x = (t >= off) ? sb[t - off] : 0;
        __syncthreads();
        sb[t] += x;
        __syncthreads();
    }
    if (t < nbuk) {
        int ex = sb[t] - v;
        bucket_base[t] = ex;
        bucket_cursor[t] = ex;
    }
    if (t == 0) {
        bucket_base[nbuk] = sb[255];
        rowstart[N] = E;
    }
}

// A3: bin edges into coarse-bucket segments of bstage, LDS-staged burst writes.
// Record: {src | (dst&255)<<16, val-bits}  (valid since N <= 65536)
__global__ __launch_bounds__(256) void binA_kernel(const int* __restrict__ src,
                                                   const int* __restrict__ dst,
                                                   const float* __restrict__ vals,
                                                   int* __restrict__ bucket_cursor,
                                                   int2* __restrict__ bstage,
                                                   int E, int nbuk) {
    __shared__ int hist[NBUK_MAX];
    __shared__ int lbase[NBUK_MAX + 1];
    __shared__ int gbase[NBUK_MAX];
    __shared__ int cur[NBUK_MAX];
    __shared__ int scanbuf[256];
    __shared__ int2 stage[ATILE];
    const int tid = threadIdx.x;
    const int t0 = blockIdx.x * ATILE;
    const int cnt = min(ATILE, E - t0);

    if (tid < nbuk) hist[tid] = 0;
    __syncthreads();

    int s8[8], d8[8], v8[8];
#pragma unroll
    for (int k = 0; k < 8; ++k) {
        const int li = k * 256 + tid;
        const bool ok = li < cnt;
        const int idx = t0 + li;
        s8[k] = ok ? src[idx] : 0;
        d8[k] = ok ? dst[idx] : 0;
        v8[k] = ok ? ((const int*)vals)[idx] : 0;
        if (ok) atomicAdd(&hist[d8[k] >> 8], 1);
    }
    __syncthreads();
    // exclusive scan of hist
    const int h = (tid < nbuk) ? hist[tid] : 0;
    scanbuf[tid] = h;
    __syncthreads();
    for (int off = 1; off < 256; off <<= 1) {
        int x = (tid >= off) ? scanbuf[tid - off] : 0;
        __syncthreads();
        scanbuf[tid] += x;
        __syncthreads();
    }
    if (tid < nbuk) {
        const int ex = scanbuf[tid] - h;
        lbase[tid] = ex;
        cur[tid] = ex;
        gbase[tid] = h ? atomicAdd(&bucket_cursor[tid], h) : 0;
    }
    if (tid == 0) lbase[nbuk] = cnt;
    __syncthreads();
    // LDS re-binning
#pragma unroll
    for (int k = 0; k < 8; ++k) {
        if ((k * 256 + tid) < cnt) {
            const int b = d8[k] >> 8;
            const int lp = atomicAdd(&cur[b], 1);
            stage[lp] = make_int2((s8[k] & 0xffff) | ((d8[k] & 255) << 16), v8[k]);
        }
    }
    __syncthreads();
    // burst copy-out (binary search for bucket of slot i)
    for (int i = tid; i < cnt; i += 256) {
        int lo = 0, hi = nbuk;
        while (hi - lo > 1) {
            const int mid = (lo + hi) >> 1;
            if (lbase[mid] <= i) lo = mid; else hi = mid;
        }
        bstage[gbase[lo] + (i - lbase[lo])] = stage[i];
    }
}

// B: per-bucket CSR finalize — per-node degrees, rowstart, and L2-local scatter.
__global__ __launch_bounds__(256) void binB_kernel(const int2* __restrict__ bstage,
                                                   const int* __restrict__ bucket_base,
                                                   int* __restrict__ rowstart,
                                                   int2* __restrict__ edata, int N) {
    __shared__ int deg_l[256];
    __shared__ int pfx[256];
    const int b = blockIdx.x;
    const int base = bucket_base[b], end = bucket_base[b + 1];
    const int n0 = b << 8;
    const int tid = threadIdx.x;
    deg_l[tid] = 0;
    __syncthreads();
    for (int i = base + tid; i < end; i += 256)
        atomicAdd(&deg_l[(bstage[i].x >> 16) & 255], 1);
    __syncthreads();
    const int v = deg_l[tid];
    pfx[tid] = v;
    __syncthreads();
    for (int off = 1; off < 256; off <<= 1) {
        int x = (tid >= off) ? pfx[tid - off] : 0;
        __syncthreads();
        pfx[tid] += x;
        __syncthreads();
    }
    const int ex = pfx[tid] - v;
    if (n0 + tid < N) rowstart[n0 + tid] = base + ex;
    __syncthreads();
    deg_l[tid] = ex;  // reuse as relative cursor
    __syncthreads();
    for (int i = base + tid; i < end; i += 256) {
        const int2 r = bstage[i];
        const int lp = atomicAdd(&deg_l[(r.x >> 16) & 255], 1);
        edata[base + lp] = make_int2(r.x & 0xffff, r.y);
    }
}

// h[i] = bf16( bias + sum_{e in CSR[i]} val_e * xw[src_e] )  (one wave per node, xw bf16)
__global__ __launch_bounds__(256) void gather_kernel(const unsigned short* __restrict__ xw,
                                                     const int* __restrict__ rowstart,
                                                     const int2* __restrict__ edata,
                                                     const float* __restrict__ bias,
                                                     unsigned short* __restrict__ h, int N) {
    const int node = blockIdx.x * 4 + (threadIdx.x >> 6);
    const int lane = threadIdx.x & 63;
    if (node >= N) return;
    const int s0 = rowstart[node], s1 = rowstart[node + 1];
    float2 acc = *(const float2*)(bias + lane * 2);
    int e = s0;
    for (; e + 4 <= s1; e += 4) {
        int2 e0 = edata[e], e1 = edata[e + 1], e2 = edata[e + 2], e3 = edata[e + 3];
        unsigned xa = *(const unsigned*)(xw + (size_t)e0.x * 128 + lane * 2);
        unsigned xb = *(const unsigned*)(xw + (size_t)e1.x * 128 + lane * 2);
        unsigned xc = *(const unsigned*)(xw + (size_t)e2.x * 128 + lane * 2);
        unsigned xd = *(const unsigned*)(xw + (size_t)e3.x * 128 + lane * 2);
        float va = __builtin_bit_cast(float, e0.y), vb = __builtin_bit_cast(float, e1.y);
        float vc = __builtin_bit_cast(float, e2.y), vd = __builtin_bit_cast(float, e3.y);
        acc.x = fmaf(va, bflo(xa), acc.x);
        acc.y = fmaf(va, bfhi(xa), acc.y);
        acc.x = fmaf(vb, bflo(xb), acc.x);
        acc.y = fmaf(vb, bfhi(xb), acc.y);
        acc.x = fmaf(vc, bflo(xc), acc.x);
        acc.y = fmaf(vc, bfhi(xc), acc.y);
        acc.x = fmaf(vd, bflo(xd), acc.x);
        acc.y = fmaf(vd, bfhi(xd), acc.y);
    }
    for (; e < s1; ++e) {
        int2 e0 = edata[e];
        float va = __builtin_bit_cast(float, e0.y);
        unsigned xa = *(const unsigned*)(xw + (size_t)e0.x * 128 + lane * 2);
        acc.x = fmaf(va, bflo(xa), acc.x);
        acc.y = fmaf(va, bfhi(xa), acc.y);
    }
    unsigned pk = (unsigned)f2bf(acc.x) | ((unsigned)f2bf(acc.y) << 16);
    *(unsigned*)(h + (size_t)node * 128 + lane * 2) = pk;
}

// MFMA GEMM: out[N,128] = act( concat(actA(A), actB(B2[rmap])) @ W (+bias) )
// A, B2 bf16; Wt pre-transposed bf16 Wt[c*K+k]. 64 rows/block, 4 waves.
template <int K, bool LRA, bool LRB, bool LROUT, bool HASB, bool OUTBF>
__global__ __launch_bounds__(256) void mgemm_kernel(const unsigned short* __restrict__ A,
                                                    const unsigned short* __restrict__ B2,
                                                    const int* __restrict__ rmap,
                                                    const unsigned short* __restrict__ Wt,
                                                    const float* __restrict__ bias,
                                                    void* __restrict__ outv, int N) {
    __shared__ short As[64 * 32];   // [row][k] bf16, 4 KB
    __shared__ short Bs[128 * 32];  // [col][k] bf16, 8 KB
    const int tid = threadIdx.x;
    const int wv = tid >> 6, lane = tid & 63;
    const int lr = lane & 15, lg = lane >> 4;
    const int row0 = blockIdx.x * 64;

    // A-staging: 4 threads/row, 8 bf16 each (16 B)
    const int arow = tid >> 2, apart = tid & 3;
    const int grow = row0 + arow;
    const int gr = grow < N ? grow : N - 1;
    const int rr = (K > 128) ? rmap[gr] : 0;
    // B-staging: 2 threads/col, 16 bf16 each
    const int bc = tid & 127, bhalf = (tid >> 7) * 16;

    f32x4 acc[8];
#pragma unroll
    for (int t = 0; t < 8; ++t) acc[t] = (f32x4){0.f, 0.f, 0.f, 0.f};

#pragma unroll 1   // keep live ranges short (round-1 spill lesson)
    for (int kc = 0; kc < K / 32; ++kc) {
        const int k0 = kc * 32;
        // ---- stage A chunk (bf16, fused lrelu/concat) ----
        {
            const int kbase = k0 + apart * 8;
            const bool inA = kbase < 128;
            const unsigned short* sp = inA ? A + (size_t)gr * 128 + kbase
                                           : B2 + (size_t)rr * 128 + (kbase - 128);
            short8 v = *(const short8*)sp;
            const bool dolr = inA ? LRA : LRB;
            if (dolr) {
#pragma unroll
                for (int j = 0; j < 8; ++j)
                    v[j] = (short)f2bf(lrelu(bf2f((unsigned short)v[j])));
            }
            *(short8*)&As[arow * 32 + apart * 8] = v;
        }
        // ---- stage B chunk from Wt ----
        {
            const unsigned short* wsrc = Wt + (size_t)bc * K + k0 + bhalf;
            *(short8*)&Bs[bc * 32 + bhalf]     = *(const short8*)wsrc;
            *(short8*)&Bs[bc * 32 + bhalf + 8] = *(const short8*)(wsrc + 8);
        }
        __syncthreads();
        // ---- MFMA: wave wv does rows wv*16..+16 x 8 col-tiles ----
        short8 af = *(short8*)&As[(wv * 16 + lr) * 32 + lg * 8];
#pragma unroll
        for (int t = 0; t < 8; ++t) {
            short8 bf = *(short8*)&Bs[(t * 16 + lr) * 32 + lg * 8];
            acc[t] = __builtin_amdgcn_mfma_f32_16x16x32_bf16(af, bf, acc[t], 0, 0, 0);
        }
        __syncthreads();
    }

    // ---- epilogue: C/D layout col=lane&15, row=(lane>>4)*4+reg ----
#pragma unroll
    for (int t = 0; t < 8; ++t) {
#pragma unroll
        for (int r = 0; r < 4; ++r) {
            int grr = row0 + wv * 16 + lg * 4 + r;
            if (grr < N) {
                float v = acc[t][r];
                if (HASB) v += bias[t * 16 + lr];
                if (LROUT) v = lrelu(v);
                if (OUTBF)
                    ((unsigned short*)outv)[(size_t)grr * 128 + t * 16 + lr] = f2bf(v);
                else
                    ((float*)outv)[(size_t)grr * 128 + t * 16 + lr] = v;
            }
        }
    }
}

extern "C" void kernel_launch(void* const* d_in, const int* in_sizes, int n_in,
                              void* d_out, int out_size, void* d_ws, size_t ws_size,
                              hipStream_t stream) {
    const float* features = (const float*)d_in[0];
    const float* values   = (const float*)d_in[1];
    const float* W1 = (const float*)d_in[2];
    const float* b1 = (const float*)d_in[3];
    const float* W2 = (const float*)d_in[4];
    const float* b2 = (const float*)d_in[5];
    const float* Wl = (const float*)d_in[6];
    const float* bl = (const float*)d_in[7];
    const int* adjs     = (const int*)d_in[8];
    const int* root_idx = (const int*)d_in[9];
    const int* batch    = (const int*)d_in[12];
    float* out = (float*)d_out;

    const int N = in_sizes[0] / 128;   // 50000 (< 65536: packed-record assumption)
    const int E = in_sizes[1];
    const int* src = adjs;
    const int* dst = adjs + E;
    const int nbuk = (N + 255) >> 8;   // 196

    const size_t nf = (size_t)N * 128;
    unsigned short* bufA   = (unsigned short*)d_ws;  // xw1/xw2 bf16 [N*128]
    unsigned short* h1     = bufA + nf;              // conv1 out bf16 (raw, +b1)
    unsigned short* h2     = h1 + nf;                // conv2 out bf16 (pre-lrelu, +b2)
    unsigned short* feat16 = h2 + nf;                // bf16 features
    unsigned short* wt1 = feat16 + nf;               // [128][128]
    unsigned short* wt2 = wt1 + 128 * 128;           // [128][256]
    unsigned short* wtl = wt2 + 256 * 128;           // [128][256]
    uintptr_t ep = ((uintptr_t)(wtl + 256 * 128) + 7) & ~(uintptr_t)7;
    int2* edata  = (int2*)ep;                        // final CSR records [E]
    int2* bstage = edata + E;                        // coarse-binned staging [E]
    int*  rmap     = (int*)(bstage + E);
    int*  rowstart = rmap + N;                       // [N+1]
    int*  bucket_count  = rowstart + N + 1;          // [nbuk]
    int*  bucket_base   = bucket_count + NBUK_MAX;   // [nbuk+1]
    int*  bucket_cursor = bucket_base + NBUK_MAX + 1;// [nbuk]

    const int gblocks = (N + 63) / 64;

    // ---- prep + two-level CSR build ----
    prep_kernel<<<1024, 256, 0, stream>>>(features, batch, root_idx, W1, W2, Wl,
                                          feat16, rmap, bucket_count, wt1, wt2, wtl,
                                          N, nbuk);
    histA_kernel<<<256, 256, 0, stream>>>(dst, bucket_count, E, nbuk);
    scanA_kernel<<<1, 256, 0, stream>>>(bucket_count, bucket_base, bucket_cursor,
                                        rowstart, N, E, nbuk);
    binA_kernel<<<(E + ATILE - 1) / ATILE, 256, 0, stream>>>(src, dst, values,
                                                             bucket_cursor, bstage, E, nbuk);
    binB_kernel<<<nbuk, 256, 0, stream>>>(bstage, bucket_base, rowstart, edata, N);

    // ---- conv1: xw1 = feat16 @ W1 ; h1 = bf16(b1 + gather) ----
    mgemm_kernel<128, false, false, false, false, true>
        <<<gblocks, 256, 0, stream>>>(feat16, nullptr, nullptr, wt1, nullptr, bufA, N);
    gather_kernel<<<(N + 3) / 4, 256, 0, stream>>>(bufA, rowstart, edata, b1, h1, N);

    // ---- conv2: xw2 = concat(lrelu(h1), lrelu(feat16[root])) @ W2 ; h2 = bf16(b2 + gather) ----
    mgemm_kernel<256, true, true, false, false, true>
        <<<gblocks, 256, 0, stream>>>(h1, feat16, rmap, wt2, nullptr, bufA, N);
    gather_kernel<<<(N + 3) / 4, 256, 0, stream>>>(bufA, rowstart, edata, b2, h2, N);

    // ---- out = lrelu( concat(lrelu(h2), h1[root]) @ Wl + bl )  (f32 out) ----
    mgemm_kernel<256, true, false, true, true, false>
        <<<gblocks, 256, 0, stream>>>(h2, h1, rmap, wtl, bl, out, N);
}

// Round 10
// 268.056 us; speedup vs baseline: 62.4864x; 1.0183x over previous
//
#include <hip/hip_runtime.h>
#include <hip/hip_bf16.h>

#define NEG_SLOPE 0.01f
#define NBUK_MAX 256
#define ATILE 2048

typedef __attribute__((ext_vector_type(8))) short short8;
typedef __attribute__((ext_vector_type(4))) float f32x4;

__device__ __forceinline__ float lrelu(float x) { return x > 0.f ? x : NEG_SLOPE * x; }

// f32 -> bf16 bits, round-to-nearest-even
__device__ __forceinline__ unsigned short f2bf(float f) {
    unsigned u = __builtin_bit_cast(unsigned, f);
    u += 0x7fffu + ((u >> 16) & 1u);
    return (unsigned short)(u >> 16);
}
__device__ __forceinline__ float bf2f(unsigned short h) {
    return __builtin_bit_cast(float, (unsigned)h << 16);
}
__device__ __forceinline__ float bflo(unsigned u) {
    return __builtin_bit_cast(float, u << 16);
}
__device__ __forceinline__ float bfhi(unsigned u) {
    return __builtin_bit_cast(float, u & 0xffff0000u);
}

// Fused prep: feat16 = bf16(features); rmap; bucket_count=0; transposed bf16 weights.
__global__ __launch_bounds__(256) void prep_kernel(
        const float* __restrict__ features, const int* __restrict__ batch,
        const int* __restrict__ root_idx, const float* __restrict__ W1,
        const float* __restrict__ W2, const float* __restrict__ Wl,
        unsigned short* __restrict__ feat16, int* __restrict__ rmap,
        int* __restrict__ bucket_count, unsigned short* __restrict__ wt1,
        unsigned short* __restrict__ wt2, unsigned short* __restrict__ wtl,
        int N, int nbuk) {
    const int total = N * 32;  // float4 groups of features
    for (int i = blockIdx.x * blockDim.x + threadIdx.x; i < total;
         i += gridDim.x * blockDim.x) {
        float4 v = *(const float4*)(features + (size_t)i * 4);
        ushort4 p;
        p.x = f2bf(v.x); p.y = f2bf(v.y); p.z = f2bf(v.z); p.w = f2bf(v.w);
        *(ushort4*)(feat16 + (size_t)i * 4) = p;
        if (i < N) rmap[i] = root_idx[batch[i]];
        if (i < nbuk) bucket_count[i] = 0;
        if (i < 128 * 128) {
            int k = i >> 7, c = i & 127;
            wt1[c * 128 + k] = f2bf(W1[i]);
        }
        if (i < 256 * 128) {
            int k = i >> 7, c = i & 127;
            wt2[c * 256 + k] = f2bf(W2[i]);
            wtl[c * 256 + k] = f2bf(Wl[i]);
        }
    }
}

// A1: coarse histogram of dst>>8 (LDS-aggregated)
__global__ __launch_bounds__(256) void histA_kernel(const int* __restrict__ dst,
                                                    int* __restrict__ bucket_count,
                                                    int E, int nbuk) {
    __shared__ int hist[NBUK_MAX];
    if (threadIdx.x < nbuk) hist[threadIdx.x] = 0;
    __syncthreads();
    for (int e = blockIdx.x * blockDim.x + threadIdx.x; e < E; e += gridDim.x * blockDim.x)
        atomicAdd(&hist[dst[e] >> 8], 1);
    __syncthreads();
    if (threadIdx.x < nbuk) {
        int v = hist[threadIdx.x];
        if (v) atomicAdd(&bucket_count[threadIdx.x], v);
    }
}

// A2: scan bucket counts -> bucket_base/cursor; rowstart[N]=E
__global__ __launch_bounds__(256) void scanA_kernel(const int* __restrict__ bucket_count,
                                                    int* __restrict__ bucket_base,
                                                    int* __restrict__ bucket_cursor,
                                                    int* __restrict__ rowstart,
                                                    int N, int E, int nbuk) {
    __shared__ int sb[256];
    const int t = threadIdx.x;
    int v = (t < nbuk) ? bucket_count[t] : 0;
    sb[t] = v;
    __syncthreads();
    for (int off = 1; off < 256; off <<= 1) {
        int x = (t >= off) ? sb[t - off] : 0;
        __syncthreads();
        sb[t] += x;
        __syncthreads();
    }
    if (t < nbuk) {
        int ex = sb[t] - v;
        bucket_base[t] = ex;
        bucket_cursor[t] = ex;
    }
    if (t == 0) {
        bucket_base[nbuk] = sb[255];
        rowstart[N] = E;
    }
}

// A3: bin edges into coarse-bucket segments of bstage, LDS-staged burst writes.
// Record: {src | (dst&255)<<16, val-bits}  (valid since N <= 65536)
__global__ __launch_bounds__(256) void binA_kernel(const int* __restrict__ src,
                                                   const int* __restrict__ dst,
                                                   const float* __restrict__ vals,
                                                   int* __restrict__ bucket_cursor,
                                                   int2* __restrict__ bstage,
                                                   int E, int nbuk) {
    __shared__ int hist[NBUK_MAX];
    __shared__ int lbase[NBUK_MAX + 1];
    __shared__ int gbase[NBUK_MAX];
    __shared__ int cur[NBUK_MAX];
    __shared__ int scanbuf[256];
    __shared__ int2 stage[ATILE];
    const int tid = threadIdx.x;
    const int t0 = blockIdx.x * ATILE;
    const int cnt = min(ATILE, E - t0);

    if (tid < nbuk) hist[tid] = 0;
    __syncthreads();

    int s8[8], d8[8], v8[8];
#pragma unroll
    for (int k = 0; k < 8; ++k) {
        const int li = k * 256 + tid;
        const bool ok = li < cnt;
        const int idx = t0 + li;
        s8[k] = ok ? src[idx] : 0;
        d8[k] = ok ? dst[idx] : 0;
        v8[k] = ok ? ((const int*)vals)[idx] : 0;
        if (ok) atomicAdd(&hist[d8[k] >> 8], 1);
    }
    __syncthreads();
    // exclusive scan of hist
    const int h = (tid < nbuk) ? hist[tid] : 0;
    scanbuf[tid] = h;
    __syncthreads();
    for (int off = 1; off < 256; off <<= 1) {
        int x = (tid >= off) ? scanbuf[tid - off] : 0;
        __syncthreads();
        scanbuf[tid] += x;
        __syncthreads();
    }
    if (tid < nbuk) {
        const int ex = scanbuf[tid] - h;
        lbase[tid] = ex;
        cur[tid] = ex;
        gbase[tid] = h ? atomicAdd(&bucket_cursor[tid], h) : 0;
    }
    if (tid == 0) lbase[nbuk] = cnt;
    __syncthreads();
    // LDS re-binning
#pragma unroll
    for (int k = 0; k < 8; ++k) {
        if ((k * 256 + tid) < cnt) {
            const int b = d8[k] >> 8;
            const int lp = atomicAdd(&cur[b], 1);
            stage[lp] = make_int2((s8[k] & 0xffff) | ((d8[k] & 255) << 16), v8[k]);
        }
    }
    __syncthreads();
    // burst copy-out (binary search for bucket of slot i)
    for (int i = tid; i < cnt; i += 256) {
        int lo = 0, hi = nbuk;
        while (hi - lo > 1) {
            const int mid = (lo + hi) >> 1;
            if (lbase[mid] <= i) lo = mid; else hi = mid;
        }
        bstage[gbase[lo] + (i - lbase[lo])] = stage[i];
    }
}

// B: per-bucket CSR finalize — per-node degrees, rowstart, and L2-local scatter.
__global__ __launch_bounds__(256) void binB_kernel(const int2* __restrict__ bstage,
                                                   const int* __restrict__ bucket_base,
                                                   int* __restrict__ rowstart,
                                                   int2* __restrict__ edata, int N) {
    __shared__ int deg_l[256];
    __shared__ int pfx[256];
    const int b = blockIdx.x;
    const int base = bucket_base[b], end = bucket_base[b + 1];
    const int n0 = b << 8;
    const int tid = threadIdx.x;
    deg_l[tid] = 0;
    __syncthreads();
    for (int i = base + tid; i < end; i += 256)
        atomicAdd(&deg_l[(bstage[i].x >> 16) & 255], 1);
    __syncthreads();
    const int v = deg_l[tid];
    pfx[tid] = v;
    __syncthreads();
    for (int off = 1; off < 256; off <<= 1) {
        int x = (tid >= off) ? pfx[tid - off] : 0;
        __syncthreads();
        pfx[tid] += x;
        __syncthreads();
    }
    const int ex = pfx[tid] - v;
    if (n0 + tid < N) rowstart[n0 + tid] = base + ex;
    __syncthreads();
    deg_l[tid] = ex;  // reuse as relative cursor
    __syncthreads();
    for (int i = base + tid; i < end; i += 256) {
        const int2 r = bstage[i];
        const int lp = atomicAdd(&deg_l[(r.x >> 16) & 255], 1);
        edata[base + lp] = make_int2(r.x & 0xffff, r.y);
    }
}

// h[i] = bf16( bias + sum_{e in CSR[i]} val_e * xw[src_e] )  (one wave per node, xw bf16)
__global__ __launch_bounds__(256) void gather_kernel(const unsigned short* __restrict__ xw,
                                                     const int* __restrict__ rowstart,
                                                     const int2* __restrict__ edata,
                                                     const float* __restrict__ bias,
                                                     unsigned short* __restrict__ h, int N) {
    const int node = blockIdx.x * 4 + (threadIdx.x >> 6);
    const int lane = threadIdx.x & 63;
    if (node >= N) return;
    const int s0 = rowstart[node], s1 = rowstart[node + 1];
    float2 acc = *(const float2*)(bias + lane * 2);
    int e = s0;
    for (; e + 4 <= s1; e += 4) {
        int2 e0 = edata[e], e1 = edata[e + 1], e2 = edata[e + 2], e3 = edata[e + 3];
        unsigned xa = *(const unsigned*)(xw + (size_t)e0.x * 128 + lane * 2);
        unsigned xb = *(const unsigned*)(xw + (size_t)e1.x * 128 + lane * 2);
        unsigned xc = *(const unsigned*)(xw + (size_t)e2.x * 128 + lane * 2);
        unsigned xd = *(const unsigned*)(xw + (size_t)e3.x * 128 + lane * 2);
        float va = __builtin_bit_cast(float, e0.y), vb = __builtin_bit_cast(float, e1.y);
        float vc = __builtin_bit_cast(float, e2.y), vd = __builtin_bit_cast(float, e3.y);
        acc.x = fmaf(va, bflo(xa), acc.x);
        acc.y = fmaf(va, bfhi(xa), acc.y);
        acc.x = fmaf(vb, bflo(xb), acc.x);
        acc.y = fmaf(vb, bfhi(xb), acc.y);
        acc.x = fmaf(vc, bflo(xc), acc.x);
        acc.y = fmaf(vc, bfhi(xc), acc.y);
        acc.x = fmaf(vd, bflo(xd), acc.x);
        acc.y = fmaf(vd, bfhi(xd), acc.y);
    }
    for (; e < s1; ++e) {
        int2 e0 = edata[e];
        float va = __builtin_bit_cast(float, e0.y);
        unsigned xa = *(const unsigned*)(xw + (size_t)e0.x * 128 + lane * 2);
        acc.x = fmaf(va, bflo(xa), acc.x);
        acc.y = fmaf(va, bfhi(xa), acc.y);
    }
    unsigned pk = (unsigned)f2bf(acc.x) | ((unsigned)f2bf(acc.y) << 16);
    *(unsigned*)(h + (size_t)node * 128 + lane * 2) = pk;
}

// MFMA GEMM v2: out[N,128] = act( concat(actA(A), actB(B2[rmap])) @ W (+bias) )
// - Full Wt resident in LDS (XOR-swizzled, loaded once, ONE barrier total)
// - A fragments loaded direct global->reg (no LDS), 1-deep prefetch
// - 128 rows/block, 8 waves (512 thr), barrier-free K loop
template <int K, bool LRA, bool LRB, bool LROUT, bool HASB, bool OUTBF>
__global__ __launch_bounds__(512) void mgemm_kernel(const unsigned short* __restrict__ A,
                                                    const unsigned short* __restrict__ B2,
                                                    const int* __restrict__ rmap,
                                                    const unsigned short* __restrict__ Wt,
                                                    const float* __restrict__ bias,
                                                    void* __restrict__ outv, int N) {
    __shared__ short Bs[128 * K];  // [col][k] bf16, k XOR-swizzled by ((col&7)<<3)
    const int tid = threadIdx.x;
    const int wv = tid >> 6, lane = tid & 63;
    const int lr = lane & 15, lg = lane >> 4;
    const int row0 = blockIdx.x * 128;

    // ---- stage ALL of Wt once: 4 threads/col, K/4 shorts each ----
    {
        const int col = tid >> 2, part = tid & 3;
        const int swz = (col & 7) << 3;
#pragma unroll
        for (int i = 0; i < K / 32; ++i) {
            const int k = part * (K / 4) + i * 8;
            short8 v = *(const short8*)(Wt + (size_t)col * K + k);
            *(short8*)&Bs[col * K + (k ^ swz)] = v;
        }
    }
    __syncthreads();  // the only barrier

    const int row = row0 + wv * 16 + lr;
    const int gr = row < N ? row : N - 1;
    const int rr = (K > 128) ? rmap[gr] : 0;
    const unsigned short* aptr = A + (size_t)gr * 128;
    const unsigned short* bptr = (K > 128) ? B2 + (size_t)rr * 128 : nullptr;

    f32x4 acc[8];
#pragma unroll
    for (int t = 0; t < 8; ++t) acc[t] = (f32x4){0.f, 0.f, 0.f, 0.f};

    // raw fragment load for chunk kc (uniform A/B2 switch: boundary 128 is a
    // multiple of 32, so each chunk lies entirely on one side)
    auto loadraw = [&](int kc) -> short8 {
        const int kbase = kc * 32 + lg * 8;
        if (K == 128 || kbase < 128) return *(const short8*)(aptr + kbase);
        return *(const short8*)(bptr + (kbase - 128));
    };
    auto xform = [&](short8 v, int kc) -> short8 {
        const bool dolr = (K == 128 || kc * 32 < 128) ? LRA : LRB;
        if (dolr) {
#pragma unroll
            for (int j = 0; j < 8; ++j)
                v[j] = (short)f2bf(lrelu(bf2f((unsigned short)v[j])));
        }
        return v;
    };

    short8 raw = loadraw(0);
#pragma unroll 1   // keep live ranges short (round-1 spill lesson); 1-deep prefetch inside
    for (int kc = 0; kc < K / 32; ++kc) {
        short8 raw_nxt = (kc + 1 < K / 32) ? loadraw(kc + 1) : raw;  // issue early
        short8 af = xform(raw, kc);
        const int kb = kc * 32 + lg * 8;
#pragma unroll
        for (int t = 0; t < 8; ++t) {
            const int col = t * 16 + lr;
            short8 bf = *(short8*)&Bs[col * K + (kb ^ ((col & 7) << 3))];
            acc[t] = __builtin_amdgcn_mfma_f32_16x16x32_bf16(af, bf, acc[t], 0, 0, 0);
        }
        raw = raw_nxt;
    }

    // ---- epilogue: C/D layout col=lane&15, row=(lane>>4)*4+reg ----
#pragma unroll
    for (int t = 0; t < 8; ++t) {
#pragma unroll
        for (int r = 0; r < 4; ++r) {
            int grr = row0 + wv * 16 + lg * 4 + r;
            if (grr < N) {
                float v = acc[t][r];
                if (HASB) v += bias[t * 16 + lr];
                if (LROUT) v = lrelu(v);
                if (OUTBF)
                    ((unsigned short*)outv)[(size_t)grr * 128 + t * 16 + lr] = f2bf(v);
                else
                    ((float*)outv)[(size_t)grr * 128 + t * 16 + lr] = v;
            }
        }
    }
}

extern "C" void kernel_launch(void* const* d_in, const int* in_sizes, int n_in,
                              void* d_out, int out_size, void* d_ws, size_t ws_size,
                              hipStream_t stream) {
    const float* features = (const float*)d_in[0];
    const float* values   = (const float*)d_in[1];
    const float* W1 = (const float*)d_in[2];
    const float* b1 = (const float*)d_in[3];
    const float* W2 = (const float*)d_in[4];
    const float* b2 = (const float*)d_in[5];
    const float* Wl = (const float*)d_in[6];
    const float* bl = (const float*)d_in[7];
    const int* adjs     = (const int*)d_in[8];
    const int* root_idx = (const int*)d_in[9];
    const int* batch    = (const int*)d_in[12];
    float* out = (float*)d_out;

    const int N = in_sizes[0] / 128;   // 50000 (< 65536: packed-record assumption)
    const int E = in_sizes[1];
    const int* src = adjs;
    const int* dst = adjs + E;
    const int nbuk = (N + 255) >> 8;   // 196

    const size_t nf = (size_t)N * 128;
    unsigned short* bufA   = (unsigned short*)d_ws;  // xw1/xw2 bf16 [N*128]
    unsigned short* h1     = bufA + nf;              // conv1 out bf16 (raw, +b1)
    unsigned short* h2     = h1 + nf;                // conv2 out bf16 (pre-lrelu, +b2)
    unsigned short* feat16 = h2 + nf;                // bf16 features
    unsigned short* wt1 = feat16 + nf;               // [128][128]
    unsigned short* wt2 = wt1 + 128 * 128;           // [128][256]
    unsigned short* wtl = wt2 + 256 * 128;           // [128][256]
    uintptr_t ep = ((uintptr_t)(wtl + 256 * 128) + 7) & ~(uintptr_t)7;
    int2* edata  = (int2*)ep;                        // final CSR records [E]
    int2* bstage = edata + E;                        // coarse-binned staging [E]
    int*  rmap     = (int*)(bstage + E);
    int*  rowstart = rmap + N;                       // [N+1]
    int*  bucket_count  = rowstart + N + 1;          // [nbuk]
    int*  bucket_base   = bucket_count + NBUK_MAX;   // [nbuk+1]
    int*  bucket_cursor = bucket_base + NBUK_MAX + 1;// [nbuk]

    const int gblocks = (N + 127) / 128;

    // ---- prep + two-level CSR build ----
    prep_kernel<<<1024, 256, 0, stream>>>(features, batch, root_idx, W1, W2, Wl,
                                          feat16, rmap, bucket_count, wt1, wt2, wtl,
                                          N, nbuk);
    histA_kernel<<<256, 256, 0, stream>>>(dst, bucket_count, E, nbuk);
    scanA_kernel<<<1, 256, 0, stream>>>(bucket_count, bucket_base, bucket_cursor,
                                        rowstart, N, E, nbuk);
    binA_kernel<<<(E + ATILE - 1) / ATILE, 256, 0, stream>>>(src, dst, values,
                                                             bucket_cursor, bstage, E, nbuk);
    binB_kernel<<<nbuk, 256, 0, stream>>>(bstage, bucket_base, rowstart, edata, N);

    // ---- conv1: xw1 = feat16 @ W1 ; h1 = bf16(b1 + gather) ----
    mgemm_kernel<128, false, false, false, false, true>
        <<<gblocks, 512, 0, stream>>>(feat16, nullptr, nullptr, wt1, nullptr, bufA, N);
    gather_kernel<<<(N + 3) / 4, 256, 0, stream>>>(bufA, rowstart, edata, b1, h1, N);

    // ---- conv2: xw2 = concat(lrelu(h1), lrelu(feat16[root])) @ W2 ; h2 = bf16(b2 + gather) ----
    mgemm_kernel<256, true, true, false, false, true>
        <<<gblocks, 512, 0, stream>>>(h1, feat16, rmap, wt2, nullptr, bufA, N);
    gather_kernel<<<(N + 3) / 4, 256, 0, stream>>>(bufA, rowstart, edata, b2, h2, N);

    // ---- out = lrelu( concat(lrelu(h2), h1[root]) @ Wl + bl )  (f32 out) ----
    mgemm_kernel<256, true, false, true, true, false>
        <<<gblocks, 512, 0, stream>>>(h2, h1, rmap, wtl, bl, out, N);
}

// Round 11
// 251.715 us; speedup vs baseline: 66.5431x; 1.0649x over previous
//
#include <hip/hip_runtime.h>
#include <hip/hip_bf16.h>

#define NEG_SLOPE 0.01f
#define NBUK_MAX 256
#define ATILE 2048

typedef __attribute__((ext_vector_type(8))) short short8;
typedef __attribute__((ext_vector_type(4))) float f32x4;

__device__ __forceinline__ float lrelu(float x) { return x > 0.f ? x : NEG_SLOPE * x; }

// f32 -> bf16 bits, round-to-nearest-even
__device__ __forceinline__ unsigned short f2bf(float f) {
    unsigned u = __builtin_bit_cast(unsigned, f);
    u += 0x7fffu + ((u >> 16) & 1u);
    return (unsigned short)(u >> 16);
}
__device__ __forceinline__ float bf2f(unsigned short h) {
    return __builtin_bit_cast(float, (unsigned)h << 16);
}
__device__ __forceinline__ float bflo(unsigned u) {
    return __builtin_bit_cast(float, u << 16);
}
__device__ __forceinline__ float bfhi(unsigned u) {
    return __builtin_bit_cast(float, u & 0xffff0000u);
}

// Fused prep: feat16 = bf16(features); rmap; bucket_count=0; transposed bf16 weights.
__global__ __launch_bounds__(256) void prep_kernel(
        const float* __restrict__ features, const int* __restrict__ batch,
        const int* __restrict__ root_idx, const float* __restrict__ W1,
        const float* __restrict__ W2, const float* __restrict__ Wl,
        unsigned short* __restrict__ feat16, int* __restrict__ rmap,
        int* __restrict__ bucket_count, unsigned short* __restrict__ wt1,
        unsigned short* __restrict__ wt2, unsigned short* __restrict__ wtl,
        int N, int nbuk) {
    const int total = N * 32;  // float4 groups of features
    for (int i = blockIdx.x * blockDim.x + threadIdx.x; i < total;
         i += gridDim.x * blockDim.x) {
        float4 v = *(const float4*)(features + (size_t)i * 4);
        ushort4 p;
        p.x = f2bf(v.x); p.y = f2bf(v.y); p.z = f2bf(v.z); p.w = f2bf(v.w);
        *(ushort4*)(feat16 + (size_t)i * 4) = p;
        if (i < N) rmap[i] = root_idx[batch[i]];
        if (i < nbuk) bucket_count[i] = 0;
        if (i < 128 * 128) {
            int k = i >> 7, c = i & 127;
            wt1[c * 128 + k] = f2bf(W1[i]);
        }
        if (i < 256 * 128) {
            int k = i >> 7, c = i & 127;
            wt2[c * 256 + k] = f2bf(W2[i]);
            wtl[c * 256 + k] = f2bf(Wl[i]);
        }
    }
}

// A1: coarse histogram of dst>>8 (LDS-aggregated)
__global__ __launch_bounds__(256) void histA_kernel(const int* __restrict__ dst,
                                                    int* __restrict__ bucket_count,
                                                    int E, int nbuk) {
    __shared__ int hist[NBUK_MAX];
    if (threadIdx.x < nbuk) hist[threadIdx.x] = 0;
    __syncthreads();
    for (int e = blockIdx.x * blockDim.x + threadIdx.x; e < E; e += gridDim.x * blockDim.x)
        atomicAdd(&hist[dst[e] >> 8], 1);
    __syncthreads();
    if (threadIdx.x < nbuk) {
        int v = hist[threadIdx.x];
        if (v) atomicAdd(&bucket_count[threadIdx.x], v);
    }
}

// A2: scan bucket counts -> bucket_base/cursor; rowstart[N]=E
__global__ __launch_bounds__(256) void scanA_kernel(const int* __restrict__ bucket_count,
                                                    int* __restrict__ bucket_base,
                                                    int* __restrict__ bucket_cursor,
                                                    int* __restrict__ rowstart,
                                                    int N, int E, int nbuk) {
    __shared__ int sb[256];
    const int t = threadIdx.x;
    int v = (t < nbuk) ? bucket_count[t] : 0;
    sb[t] = v;
    __syncthreads();
    for (int off = 1; off < 256; off <<= 1) {
        int x = (t >= off) ? sb[t - off] : 0;
        __syncthreads();
        sb[t] += x;
        __syncthreads();
    }
    if (t < nbuk) {
        int ex = sb[t] - v;
        bucket_base[t] = ex;
        bucket_cursor[t] = ex;
    }
    if (t == 0) {
        bucket_base[nbuk] = sb[255];
        rowstart[N] = E;
    }
}

// A3: bin edges into coarse-bucket segments of bstage, LDS-staged burst writes.
// Record: {src | (dst&255)<<16, val-bits}  (valid since N <= 65536)
__global__ __launch_bounds__(256) void binA_kernel(const int* __restrict__ src,
                                                   const int* __restrict__ dst,
                                                   const float* __restrict__ vals,
                                                   int* __restrict__ bucket_cursor,
                                                   int2* __restrict__ bstage,
                                                   int E, int nbuk) {
    __shared__ int hist[NBUK_MAX];
    __shared__ int lbase[NBUK_MAX + 1];
    __shared__ int gbase[NBUK_MAX];
    __shared__ int cur[NBUK_MAX];
    __shared__ int scanbuf[256];
    __shared__ int2 stage[ATILE];
    const int tid = threadIdx.x;
    const int t0 = blockIdx.x * ATILE;
    const int cnt = min(ATILE, E - t0);

    if (tid < nbuk) hist[tid] = 0;
    __syncthreads();

    int s8[8], d8[8], v8[8];
#pragma unroll
    for (int k = 0; k < 8; ++k) {
        const int li = k * 256 + tid;
        const bool ok = li < cnt;
        const int idx = t0 + li;
        s8[k] = ok ? src[idx] : 0;
        d8[k] = ok ? dst[idx] : 0;
        v8[k] = ok ? ((const int*)vals)[idx] : 0;
        if (ok) atomicAdd(&hist[d8[k] >> 8], 1);
    }
    __syncthreads();
    // exclusive scan of hist
    const int h = (tid < nbuk) ? hist[tid] : 0;
    scanbuf[tid] = h;
    __syncthreads();
    for (int off = 1; off < 256; off <<= 1) {
        int x = (tid >= off) ? scanbuf[tid - off] : 0;
        __syncthreads();
        scanbuf[tid] += x;
        __syncthreads();
    }
    if (tid < nbuk) {
        const int ex = scanbuf[tid] - h;
        lbase[tid] = ex;
        cur[tid] = ex;
        gbase[tid] = h ? atomicAdd(&bucket_cursor[tid], h) : 0;
    }
    if (tid == 0) lbase[nbuk] = cnt;
    __syncthreads();
    // LDS re-binning
#pragma unroll
    for (int k = 0; k < 8; ++k) {
        if ((k * 256 + tid) < cnt) {
            const int b = d8[k] >> 8;
            const int lp = atomicAdd(&cur[b], 1);
            stage[lp] = make_int2((s8[k] & 0xffff) | ((d8[k] & 255) << 16), v8[k]);
        }
    }
    __syncthreads();
    // burst copy-out (binary search for bucket of slot i)
    for (int i = tid; i < cnt; i += 256) {
        int lo = 0, hi = nbuk;
        while (hi - lo > 1) {
            const int mid = (lo + hi) >> 1;
            if (lbase[mid] <= i) lo = mid; else hi = mid;
        }
        bstage[gbase[lo] + (i - lbase[lo])] = stage[i];
    }
}

// B: per-bucket CSR finalize — per-node degrees, rowstart, and L2-local scatter.
__global__ __launch_bounds__(256) void binB_kernel(const int2* __restrict__ bstage,
                                                   const int* __restrict__ bucket_base,
                                                   int* __restrict__ rowstart,
                                                   int2* __restrict__ edata, int N) {
    __shared__ int deg_l[256];
    __shared__ int pfx[256];
    const int b = blockIdx.x;
    const int base = bucket_base[b], end = bucket_base[b + 1];
    const int n0 = b << 8;
    const int tid = threadIdx.x;
    deg_l[tid] = 0;
    __syncthreads();
    for (int i = base + tid; i < end; i += 256)
        atomicAdd(&deg_l[(bstage[i].x >> 16) & 255], 1);
    __syncthreads();
    const int v = deg_l[tid];
    pfx[tid] = v;
    __syncthreads();
    for (int off = 1; off < 256; off <<= 1) {
        int x = (tid >= off) ? pfx[tid - off] : 0;
        __syncthreads();
        pfx[tid] += x;
        __syncthreads();
    }
    const int ex = pfx[tid] - v;
    if (n0 + tid < N) rowstart[n0 + tid] = base + ex;
    __syncthreads();
    deg_l[tid] = ex;  // reuse as relative cursor
    __syncthreads();
    for (int i = base + tid; i < end; i += 256) {
        const int2 r = bstage[i];
        const int lp = atomicAdd(&deg_l[(r.x >> 16) & 255], 1);
        edata[base + lp] = make_int2(r.x & 0xffff, r.y);
    }
}

// h[i] = bf16( bias + sum_{e in CSR[i]} val_e * xw[src_e] )
// One node per 16-lane quarter-wave: each lane loads 16 B (8 bf16) per edge,
// 4 independent edge streams per wave, unroll 4 -> up to 16 row loads in flight.
__global__ __launch_bounds__(256) void gather_kernel(const unsigned short* __restrict__ xw,
                                                     const int* __restrict__ rowstart,
                                                     const int2* __restrict__ edata,
                                                     const float* __restrict__ bias,
                                                     unsigned short* __restrict__ h, int N) {
    const int node = blockIdx.x * 16 + (threadIdx.x >> 4);
    const int ql = threadIdx.x & 15;        // lane within quarter: 8 bf16 columns
    if (node >= N) return;
    const int s0 = rowstart[node], s1 = rowstart[node + 1];
    const int c0 = ql * 8;
    float acc[8];
    {
        float4 b0 = *(const float4*)(bias + c0);
        float4 b1 = *(const float4*)(bias + c0 + 4);
        acc[0] = b0.x; acc[1] = b0.y; acc[2] = b0.z; acc[3] = b0.w;
        acc[4] = b1.x; acc[5] = b1.y; acc[6] = b1.z; acc[7] = b1.w;
    }
    int e = s0;
    for (; e + 4 <= s1; e += 4) {
        int2 e0 = edata[e], e1 = edata[e + 1], e2 = edata[e + 2], e3 = edata[e + 3];
        uint4 x0 = *(const uint4*)(xw + (size_t)e0.x * 128 + c0);
        uint4 x1 = *(const uint4*)(xw + (size_t)e1.x * 128 + c0);
        uint4 x2 = *(const uint4*)(xw + (size_t)e2.x * 128 + c0);
        uint4 x3 = *(const uint4*)(xw + (size_t)e3.x * 128 + c0);
        float v0 = __builtin_bit_cast(float, e0.y), v1 = __builtin_bit_cast(float, e1.y);
        float v2 = __builtin_bit_cast(float, e2.y), v3 = __builtin_bit_cast(float, e3.y);
        const unsigned* p0 = &x0.x; const unsigned* p1 = &x1.x;
        const unsigned* p2 = &x2.x; const unsigned* p3 = &x3.x;
#pragma unroll
        for (int j = 0; j < 4; ++j) {
            acc[2 * j]     = fmaf(v0, bflo(p0[j]), acc[2 * j]);
            acc[2 * j + 1] = fmaf(v0, bfhi(p0[j]), acc[2 * j + 1]);
            acc[2 * j]     = fmaf(v1, bflo(p1[j]), acc[2 * j]);
            acc[2 * j + 1] = fmaf(v1, bfhi(p1[j]), acc[2 * j + 1]);
            acc[2 * j]     = fmaf(v2, bflo(p2[j]), acc[2 * j]);
            acc[2 * j + 1] = fmaf(v2, bfhi(p2[j]), acc[2 * j + 1]);
            acc[2 * j]     = fmaf(v3, bflo(p3[j]), acc[2 * j]);
            acc[2 * j + 1] = fmaf(v3, bfhi(p3[j]), acc[2 * j + 1]);
        }
    }
    for (; e < s1; ++e) {
        int2 e0 = edata[e];
        float v0 = __builtin_bit_cast(float, e0.y);
        uint4 x0 = *(const uint4*)(xw + (size_t)e0.x * 128 + c0);
        const unsigned* p0 = &x0.x;
#pragma unroll
        for (int j = 0; j < 4; ++j) {
            acc[2 * j]     = fmaf(v0, bflo(p0[j]), acc[2 * j]);
            acc[2 * j + 1] = fmaf(v0, bfhi(p0[j]), acc[2 * j + 1]);
        }
    }
    uint4 o;
    o.x = (unsigned)f2bf(acc[0]) | ((unsigned)f2bf(acc[1]) << 16);
    o.y = (unsigned)f2bf(acc[2]) | ((unsigned)f2bf(acc[3]) << 16);
    o.z = (unsigned)f2bf(acc[4]) | ((unsigned)f2bf(acc[5]) << 16);
    o.w = (unsigned)f2bf(acc[6]) | ((unsigned)f2bf(acc[7]) << 16);
    *(uint4*)(h + (size_t)node * 128 + c0) = o;
}

// MFMA GEMM v2: out[N,128] = act( concat(actA(A), actB(B2[rmap])) @ W (+bias) )
// - Full Wt resident in LDS (XOR-swizzled, loaded once, ONE barrier total)
// - A fragments loaded direct global->reg (no LDS), 1-deep prefetch
// - 128 rows/block, 8 waves (512 thr), barrier-free K loop
template <int K, bool LRA, bool LRB, bool LROUT, bool HASB, bool OUTBF>
__global__ __launch_bounds__(512) void mgemm_kernel(const unsigned short* __restrict__ A,
                                                    const unsigned short* __restrict__ B2,
                                                    const int* __restrict__ rmap,
                                                    const unsigned short* __restrict__ Wt,
                                                    const float* __restrict__ bias,
                                                    void* __restrict__ outv, int N) {
    __shared__ short Bs[128 * K];  // [col][k] bf16, k XOR-swizzled by ((col&7)<<3)
    const int tid = threadIdx.x;
    const int wv = tid >> 6, lane = tid & 63;
    const int lr = lane & 15, lg = lane >> 4;
    const int row0 = blockIdx.x * 128;

    // ---- stage ALL of Wt once: 4 threads/col, K/4 shorts each ----
    {
        const int col = tid >> 2, part = tid & 3;
        const int swz = (col & 7) << 3;
#pragma unroll
        for (int i = 0; i < K / 32; ++i) {
            const int k = part * (K / 4) + i * 8;
            short8 v = *(const short8*)(Wt + (size_t)col * K + k);
            *(short8*)&Bs[col * K + (k ^ swz)] = v;
        }
    }
    __syncthreads();  // the only barrier

    const int row = row0 + wv * 16 + lr;
    const int gr = row < N ? row : N - 1;
    const int rr = (K > 128) ? rmap[gr] : 0;
    const unsigned short* aptr = A + (size_t)gr * 128;
    const unsigned short* bptr = (K > 128) ? B2 + (size_t)rr * 128 : nullptr;

    f32x4 acc[8];
#pragma unroll
    for (int t = 0; t < 8; ++t) acc[t] = (f32x4){0.f, 0.f, 0.f, 0.f};

    // raw fragment load for chunk kc (uniform A/B2 switch: boundary 128 is a
    // multiple of 32, so each chunk lies entirely on one side)
    auto loadraw = [&](int kc) -> short8 {
        const int kbase = kc * 32 + lg * 8;
        if (K == 128 || kbase < 128) return *(const short8*)(aptr + kbase);
        return *(const short8*)(bptr + (kbase - 128));
    };
    auto xform = [&](short8 v, int kc) -> short8 {
        const bool dolr = (K == 128 || kc * 32 < 128) ? LRA : LRB;
        if (dolr) {
#pragma unroll
            for (int j = 0; j < 8; ++j)
                v[j] = (short)f2bf(lrelu(bf2f((unsigned short)v[j])));
        }
        return v;
    };

    short8 raw = loadraw(0);
#pragma unroll 1   // keep live ranges short (round-1 spill lesson); 1-deep prefetch inside
    for (int kc = 0; kc < K / 32; ++kc) {
        short8 raw_nxt = (kc + 1 < K / 32) ? loadraw(kc + 1) : raw;  // issue early
        short8 af = xform(raw, kc);
        const int kb = kc * 32 + lg * 8;
#pragma unroll
        for (int t = 0; t < 8; ++t) {
            const int col = t * 16 + lr;
            short8 bf = *(short8*)&Bs[col * K + (kb ^ ((col & 7) << 3))];
            acc[t] = __builtin_amdgcn_mfma_f32_16x16x32_bf16(af, bf, acc[t], 0, 0, 0);
        }
        raw = raw_nxt;
    }

    // ---- epilogue: C/D layout col=lane&15, row=(lane>>4)*4+reg ----
#pragma unroll
    for (int t = 0; t < 8; ++t) {
#pragma unroll
        for (int r = 0; r < 4; ++r) {
            int grr = row0 + wv * 16 + lg * 4 + r;
            if (grr < N) {
                float v = acc[t][r];
                if (HASB) v += bias[t * 16 + lr];
                if (LROUT) v = lrelu(v);
                if (OUTBF)
                    ((unsigned short*)outv)[(size_t)grr * 128 + t * 16 + lr] = f2bf(v);
                else
                    ((float*)outv)[(size_t)grr * 128 + t * 16 + lr] = v;
            }
        }
    }
}

extern "C" void kernel_launch(void* const* d_in, const int* in_sizes, int n_in,
                              void* d_out, int out_size, void* d_ws, size_t ws_size,
                              hipStream_t stream) {
    const float* features = (const float*)d_in[0];
    const float* values   = (const float*)d_in[1];
    const float* W1 = (const float*)d_in[2];
    const float* b1 = (const float*)d_in[3];
    const float* W2 = (const float*)d_in[4];
    const float* b2 = (const float*)d_in[5];
    const float* Wl = (const float*)d_in[6];
    const float* bl = (const float*)d_in[7];
    const int* adjs     = (const int*)d_in[8];
    const int* root_idx = (const int*)d_in[9];
    const int* batch    = (const int*)d_in[12];
    float* out = (float*)d_out;

    const int N = in_sizes[0] / 128;   // 50000 (< 65536: packed-record assumption)
    const int E = in_sizes[1];
    const int* src = adjs;
    const int* dst = adjs + E;
    const int nbuk = (N + 255) >> 8;   // 196

    const size_t nf = (size_t)N * 128;
    unsigned short* bufA   = (unsigned short*)d_ws;  // xw1/xw2 bf16 [N*128]
    unsigned short* h1     = bufA + nf;              // conv1 out bf16 (raw, +b1)
    unsigned short* h2     = h1 + nf;                // conv2 out bf16 (pre-lrelu, +b2)
    unsigned short* feat16 = h2 + nf;                // bf16 features
    unsigned short* wt1 = feat16 + nf;               // [128][128]
    unsigned short* wt2 = wt1 + 128 * 128;           // [128][256]
    unsigned short* wtl = wt2 + 256 * 128;           // [128][256]
    uintptr_t ep = ((uintptr_t)(wtl + 256 * 128) + 7) & ~(uintptr_t)7;
    int2* edata  = (int2*)ep;                        // final CSR records [E]
    int2* bstage = edata + E;                        // coarse-binned staging [E]
    int*  rmap     = (int*)(bstage + E);
    int*  rowstart = rmap + N;                       // [N+1]
    int*  bucket_count  = rowstart + N + 1;          // [nbuk]
    int*  bucket_base   = bucket_count + NBUK_MAX;   // [nbuk+1]
    int*  bucket_cursor = bucket_base + NBUK_MAX + 1;// [nbuk]

    const int gblocks = (N + 127) / 128;

    // ---- prep + two-level CSR build ----
    prep_kernel<<<1024, 256, 0, stream>>>(features, batch, root_idx, W1, W2, Wl,
                                          feat16, rmap, bucket_count, wt1, wt2, wtl,
                                          N, nbuk);
    histA_kernel<<<256, 256, 0, stream>>>(dst, bucket_count, E, nbuk);
    scanA_kernel<<<1, 256, 0, stream>>>(bucket_count, bucket_base, bucket_cursor,
                                        rowstart, N, E, nbuk);
    binA_kernel<<<(E + ATILE - 1) / ATILE, 256, 0, stream>>>(src, dst, values,
                                                             bucket_cursor, bstage, E, nbuk);
    binB_kernel<<<nbuk, 256, 0, stream>>>(bstage, bucket_base, rowstart, edata, N);

    // ---- conv1: xw1 = feat16 @ W1 ; h1 = bf16(b1 + gather) ----
    mgemm_kernel<128, false, false, false, false, true>
        <<<gblocks, 512, 0, stream>>>(feat16, nullptr, nullptr, wt1, nullptr, bufA, N);
    gather_kernel<<<(N + 15) / 16, 256, 0, stream>>>(bufA, rowstart, edata, b1, h1, N);

    // ---- conv2: xw2 = concat(lrelu(h1), lrelu(feat16[root])) @ W2 ; h2 = bf16(b2 + gather) ----
    mgemm_kernel<256, true, true, false, false, true>
        <<<gblocks, 512, 0, stream>>>(h1, feat16, rmap, wt2, nullptr, bufA, N);
    gather_kernel<<<(N + 15) / 16, 256, 0, stream>>>(bufA, rowstart, edata, b2, h2, N);

    // ---- out = lrelu( concat(lrelu(h2), h1[root]) @ Wl + bl )  (f32 out) ----
    mgemm_kernel<256, true, false, true, true, false>
        <<<gblocks, 512, 0, stream>>>(h2, h1, rmap, wtl, bl, out, N);
}